// Round 9
// baseline (921.787 us; speedup 1.0000x reference)
//
#include <hip/hip_runtime.h>

// ---------------------------------------------------------------------------
// SEAL GNN pipeline, fp32.
// R9: occupancy/MLP fix for the gather kernels (R8 showed FETCH is invariant;
// the gathers are latency-bound at low occupancy):
//   - gemm_n64 / gemm_agg_n64: W read straight from global (L1-resident 16KB
//     broadcast) instead of LDS -> LDS 33.8->17.4 KB -> 8 blocks/CU (2x occ).
//   - segmean_agg: 256 threads = 4 node-parallel lane groups per graph
//     (4x memory-level parallelism), LDS reduction of partials.
// ---------------------------------------------------------------------------

typedef float nf4 __attribute__((ext_vector_type(4)));

__global__ void hist_kernel(const int* __restrict__ dst, int* __restrict__ hist, int E) {
    int e = blockIdx.x * blockDim.x + threadIdx.x;
    if (e < E) atomicAdd(&hist[dst[e]], 1);
}

__global__ void finalize_deg(const int* __restrict__ hist, float* __restrict__ dinv,
                             float* __restrict__ drecip, int n) {
    int i = blockIdx.x * blockDim.x + threadIdx.x;
    if (i < n) {
        float c = (float)hist[i] + 1.0f;   // self-loop included
        dinv[i]   = rsqrtf(c);
        drecip[i] = 1.0f / c;
    }
}

// Exclusive scan, stage 1: 1024 counts per 256-thread block.
__global__ __launch_bounds__(256) void scan1(const int* __restrict__ cnt, int* __restrict__ pre,
                                             int* __restrict__ bsum, int n) {
    __shared__ int s[256];
    int base = blockIdx.x * 1024;
    int t = threadIdx.x;
    int v[4];
    int loc = 0;
#pragma unroll
    for (int j = 0; j < 4; j++) {
        int i = base + t * 4 + j;
        v[j] = (i < n) ? cnt[i] : 0;
        loc += v[j];
    }
    s[t] = loc;
    __syncthreads();
    for (int off = 1; off < 256; off <<= 1) {
        int x = (t >= off) ? s[t - off] : 0;
        __syncthreads();
        s[t] += x;
        __syncthreads();
    }
    int run = s[t] - loc;
    if (t == 255) bsum[blockIdx.x] = s[255];
#pragma unroll
    for (int j = 0; j < 4; j++) {
        int i = base + t * 4 + j;
        if (i < n) pre[i] = run;
        run += v[j];
    }
}

// Stage 2: exclusive scan of block sums in place (nb <= 512).
__global__ __launch_bounds__(512) void scan2(int* __restrict__ bsum, int nb) {
    __shared__ int s[512];
    int t = threadIdx.x;
    int v = (t < nb) ? bsum[t] : 0;
    s[t] = v;
    __syncthreads();
    for (int off = 1; off < 512; off <<= 1) {
        int x = (t >= off) ? s[t - off] : 0;
        __syncthreads();
        s[t] += x;
        __syncthreads();
    }
    if (t < nb) bsum[t] = s[t] - v;
}

// Stage 3: add block offsets; also initializes cursor; writes rowptr[n] = E.
__global__ void scan3(int* __restrict__ pre, const int* __restrict__ bsum,
                      int* __restrict__ cursor, int n, int E) {
    int i = blockIdx.x * blockDim.x + threadIdx.x;
    if (i < n) {
        int v = pre[i] + bsum[i >> 10];
        pre[i] = v;
        cursor[i] = v;
    }
    if (i == 0) pre[n] = E;
}

// XCD-bucketed scatter (see R6 comment).
__global__ __launch_bounds__(256) void scatter_xcd(const int* __restrict__ src,
                                                   const int* __restrict__ dst,
                                                   int* __restrict__ cursor,
                                                   int* __restrict__ col,
                                                   int E, int per_chunk, int npx) {
    int bucket = blockIdx.x & 7;
    int chunk  = blockIdx.x >> 3;
    int lo = bucket * npx;
    int hi = lo + npx;
    int e0 = chunk * per_chunk;
    int e1 = min(e0 + per_chunk, E);
    for (int e = e0 + threadIdx.x; e < e1; e += 256) {
        int d = dst[e];
        if (d < lo || d >= hi) continue;
        int p = atomicAdd(&cursor[d], 1);
        col[p] = src[e];
    }
}

// Simple scatter for the tiny macro graph.
__global__ void scatter_kernel(const int* __restrict__ src, const int* __restrict__ dst,
                               int* __restrict__ cursor, int* __restrict__ col, int E) {
    int e = blockIdx.x * blockDim.x + threadIdx.x;
    if (e >= E) return;
    int p = atomicAdd(&cursor[dst[e]], 1);
    col[p] = src[e];
}

// Macro aggregation with fused BatchNorm(eval)+ReLU.
__global__ __launch_bounds__(256) void csr_agg_bn128(const int* __restrict__ rowptr,
                                                     const int* __restrict__ col,
                                                     const float* __restrict__ A,
                                                     const float* __restrict__ bias,
                                                     const float* __restrict__ dinv,
                                                     const float* __restrict__ gam,
                                                     const float* __restrict__ bet,
                                                     const float* __restrict__ mean,
                                                     const float* __restrict__ var,
                                                     float* __restrict__ Z, int N) {
    constexpr int F = 128, TPN = 32, NPB = 8;
    int node = blockIdx.x * NPB + threadIdx.x / TPN;
    int lane = threadIdx.x % TPN;
    if (node >= N) return;
    int c = lane * 4;
    float4 acc = *(const float4*)&A[(size_t)node * F + c];
    int e0 = rowptr[node], e1 = rowptr[node + 1];
    int e = e0;
    for (; e + 4 <= e1; e += 4) {
        int s0 = col[e + 0], s1 = col[e + 1], s2 = col[e + 2], s3 = col[e + 3];
        float4 v0 = *(const float4*)&A[(size_t)s0 * F + c];
        float4 v1 = *(const float4*)&A[(size_t)s1 * F + c];
        float4 v2 = *(const float4*)&A[(size_t)s2 * F + c];
        float4 v3 = *(const float4*)&A[(size_t)s3 * F + c];
        acc.x += v0.x + v1.x + v2.x + v3.x;
        acc.y += v0.y + v1.y + v2.y + v3.y;
        acc.z += v0.z + v1.z + v2.z + v3.z;
        acc.w += v0.w + v1.w + v2.w + v3.w;
    }
    for (; e < e1; e++) {
        int s = col[e];
        float4 v = *(const float4*)&A[(size_t)s * F + c];
        acc.x += v.x; acc.y += v.y; acc.z += v.z; acc.w += v.w;
    }
    float dv = dinv[node];
    float4 b4 = *(const float4*)&bias[c];
    float4 g4 = *(const float4*)&gam[c];
    float4 be4 = *(const float4*)&bet[c];
    float4 m4 = *(const float4*)&mean[c];
    float4 v4 = *(const float4*)&var[c];
    float4 o;
    o.x = fmaxf((acc.x * dv + b4.x - m4.x) * rsqrtf(v4.x + 1e-5f) * g4.x + be4.x, 0.f);
    o.y = fmaxf((acc.y * dv + b4.y - m4.y) * rsqrtf(v4.y + 1e-5f) * g4.y + be4.y, 0.f);
    o.z = fmaxf((acc.z * dv + b4.z - m4.z) * rsqrtf(v4.z + 1e-5f) * g4.z + be4.z, 0.f);
    o.w = fmaxf((acc.w * dv + b4.w - m4.w) * rsqrtf(v4.w + 1e-5f) * g4.w + be4.w, 0.f);
    *(float4*)&Z[(size_t)node * F + c] = o;
}

// Layer-1 GEMM: XW = (X @ W) * dinv[row]. W read from global (L1-resident).
__global__ __launch_bounds__(256) void gemm_n64(const float* __restrict__ X,
                                                const float* __restrict__ W,
                                                const float* __restrict__ dinv,
                                                float* __restrict__ XW, int N) {
    __shared__ float Xs[64][68];
    const int tid = threadIdx.x;
    const int tc = tid & 15;
    const int tr = tid >> 4;
    const int r0 = blockIdx.x * 64;

#pragma unroll
    for (int p = 0; p < 4; p++) {
        int row = p * 16 + (tid >> 4);
        int col = (tid & 15) * 4;
        float4 v = make_float4(0.f, 0.f, 0.f, 0.f);
        if (r0 + row < N) {
            nf4 nv = __builtin_nontemporal_load((const nf4*)&X[(size_t)(r0 + row) * 64 + col]);
            v = make_float4(nv.x, nv.y, nv.z, nv.w);
        }
        *(float4*)&Xs[row][col] = v;
    }
    __syncthreads();

    float acc[4][4];
#pragma unroll
    for (int i = 0; i < 4; i++)
#pragma unroll
        for (int j = 0; j < 4; j++) acc[i][j] = 0.f;

    const float* wp = W + tc * 4;
#pragma unroll 8
    for (int k = 0; k < 64; k++) {
        float4 wv = *(const float4*)&wp[k * 64];
        float x0 = Xs[tr * 4 + 0][k];
        float x1 = Xs[tr * 4 + 1][k];
        float x2 = Xs[tr * 4 + 2][k];
        float x3 = Xs[tr * 4 + 3][k];
        acc[0][0] += x0 * wv.x; acc[0][1] += x0 * wv.y; acc[0][2] += x0 * wv.z; acc[0][3] += x0 * wv.w;
        acc[1][0] += x1 * wv.x; acc[1][1] += x1 * wv.y; acc[1][2] += x1 * wv.z; acc[1][3] += x1 * wv.w;
        acc[2][0] += x2 * wv.x; acc[2][1] += x2 * wv.y; acc[2][2] += x2 * wv.z; acc[2][3] += x2 * wv.w;
        acc[3][0] += x3 * wv.x; acc[3][1] += x3 * wv.y; acc[3][2] += x3 * wv.z; acc[3][3] += x3 * wv.w;
    }

#pragma unroll
    for (int i = 0; i < 4; i++) {
        int row = r0 + tr * 4 + i;
        if (row >= N) continue;
        float dv = dinv[row];
        *(float4*)&XW[(size_t)row * 64 + tc * 4] =
            make_float4(acc[i][0] * dv, acc[i][1] * dv, acc[i][2] * dv, acc[i][3] * dv);
    }
}

// Layer-2 fused: X-tile = relu(dinv*(A[row]+sum A[col]) + b_prev) into LDS,
// then XW2 = (Xs @ W) * dinv[row]. W from global; A2 stored NT.
__global__ __launch_bounds__(256) void gemm_agg_n64(const int* __restrict__ rowptr,
                                                    const int* __restrict__ col,
                                                    const float* __restrict__ A,
                                                    const float* __restrict__ b_prev,
                                                    const float* __restrict__ W,
                                                    const float* __restrict__ dinv,
                                                    float* __restrict__ XW, int N) {
    __shared__ float Xs[64][68];
    const int tid = threadIdx.x;
    const int tc = tid & 15;
    const int tr = tid >> 4;
    const int r0 = blockIdx.x * 64;

#pragma unroll
    for (int p = 0; p < 4; p++) {
        int row = p * 16 + (tid >> 4);
        int node = r0 + row;
        int c = (tid & 15) * 4;
        float4 acc = make_float4(0.f, 0.f, 0.f, 0.f);
        if (node < N) {
            acc = *(const float4*)&A[(size_t)node * 64 + c];
            int e0 = rowptr[node], e1 = rowptr[node + 1];
            int e = e0;
            for (; e + 4 <= e1; e += 4) {
                int s0 = col[e + 0], s1 = col[e + 1], s2 = col[e + 2], s3 = col[e + 3];
                float4 v0 = *(const float4*)&A[(size_t)s0 * 64 + c];
                float4 v1 = *(const float4*)&A[(size_t)s1 * 64 + c];
                float4 v2 = *(const float4*)&A[(size_t)s2 * 64 + c];
                float4 v3 = *(const float4*)&A[(size_t)s3 * 64 + c];
                acc.x += v0.x + v1.x + v2.x + v3.x;
                acc.y += v0.y + v1.y + v2.y + v3.y;
                acc.z += v0.z + v1.z + v2.z + v3.z;
                acc.w += v0.w + v1.w + v2.w + v3.w;
            }
            for (; e < e1; e++) {
                int s = col[e];
                float4 v = *(const float4*)&A[(size_t)s * 64 + c];
                acc.x += v.x; acc.y += v.y; acc.z += v.z; acc.w += v.w;
            }
            float dv = dinv[node];
            float4 b4 = *(const float4*)&b_prev[c];
            acc.x = fmaxf(acc.x * dv + b4.x, 0.f);
            acc.y = fmaxf(acc.y * dv + b4.y, 0.f);
            acc.z = fmaxf(acc.z * dv + b4.z, 0.f);
            acc.w = fmaxf(acc.w * dv + b4.w, 0.f);
        }
        *(float4*)&Xs[row][c] = acc;
    }
    __syncthreads();

    float acc[4][4];
#pragma unroll
    for (int i = 0; i < 4; i++)
#pragma unroll
        for (int j = 0; j < 4; j++) acc[i][j] = 0.f;

    const float* wp = W + tc * 4;
#pragma unroll 8
    for (int k = 0; k < 64; k++) {
        float4 wv = *(const float4*)&wp[k * 64];
        float x0 = Xs[tr * 4 + 0][k];
        float x1 = Xs[tr * 4 + 1][k];
        float x2 = Xs[tr * 4 + 2][k];
        float x3 = Xs[tr * 4 + 3][k];
        acc[0][0] += x0 * wv.x; acc[0][1] += x0 * wv.y; acc[0][2] += x0 * wv.z; acc[0][3] += x0 * wv.w;
        acc[1][0] += x1 * wv.x; acc[1][1] += x1 * wv.y; acc[1][2] += x1 * wv.z; acc[1][3] += x1 * wv.w;
        acc[2][0] += x2 * wv.x; acc[2][1] += x2 * wv.y; acc[2][2] += x2 * wv.z; acc[2][3] += x2 * wv.w;
        acc[3][0] += x3 * wv.x; acc[3][1] += x3 * wv.y; acc[3][2] += x3 * wv.z; acc[3][3] += x3 * wv.w;
    }

#pragma unroll
    for (int i = 0; i < 4; i++) {
        int row = r0 + tr * 4 + i;
        if (row >= N) continue;
        float dv = dinv[row];
        nf4 o;
        o.x = acc[i][0] * dv; o.y = acc[i][1] * dv;
        o.z = acc[i][2] * dv; o.w = acc[i][3] * dv;
        __builtin_nontemporal_store(o, (nf4*)&XW[(size_t)row * 64 + tc * 4]);
    }
}

// Pooling fused with layer-2 aggregation. 4 node-parallel lane groups/block.
__global__ __launch_bounds__(256) void segmean_agg(const int* __restrict__ rowptr,
                                                   const int* __restrict__ col,
                                                   const float* __restrict__ A2,
                                                   const float* __restrict__ b2,
                                                   const float* __restrict__ dinv,
                                                   const int* __restrict__ batch,
                                                   float* __restrict__ M,
                                                   float* __restrict__ bscale, int N) {
    __shared__ float part[4][64];
    int g = blockIdx.x;
    int t = threadIdx.x & 63;     // feature column
    int sub = threadIdx.x >> 6;   // node-parallel group 0..3
    int lo = 0, hi = N;
    while (lo < hi) { int m = (lo + hi) >> 1; if (batch[m] < g) lo = m + 1; else hi = m; }
    int start = lo;
    hi = N;
    while (lo < hi) { int m = (lo + hi) >> 1; if (batch[m] < g + 1) lo = m + 1; else hi = m; }
    int end = lo;

    float bb = b2[t];
    float msum = 0.f;
    for (int node = start + sub; node < end; node += 4) {
        float acc = A2[(size_t)node * 64 + t];
        int e0 = rowptr[node], e1 = rowptr[node + 1];
        int e = e0;
        for (; e + 4 <= e1; e += 4) {
            int s0 = col[e + 0], s1 = col[e + 1], s2 = col[e + 2], s3 = col[e + 3];
            acc += A2[(size_t)s0 * 64 + t] + A2[(size_t)s1 * 64 + t]
                 + A2[(size_t)s2 * 64 + t] + A2[(size_t)s3 * 64 + t];
        }
        for (; e < e1; e++) acc += A2[(size_t)col[e] * 64 + t];
        msum += fmaxf(acc * dinv[node] + bb, 0.f);
    }
    part[sub][t] = msum;
    __syncthreads();
    if (sub == 0) {
        float s = part[0][t] + part[1][t] + part[2][t] + part[3][t];
        int cnt = end - start;
        float inv = (cnt > 0) ? 1.f / (float)cnt : 0.f;
        M[(size_t)g * 64 + t] = s * inv;
        if (t == 0) bscale[g] = (cnt > 0) ? 1.f : 0.f;
    }
}

// loc = M @ FW1 + bscale*Fb1   [G x 64 @ 64 x 128]; grid.y = 2 col-tiles.
__global__ __launch_bounds__(256) void loc_gemm(const float* __restrict__ M,
                                                const float* __restrict__ FW1,
                                                const float* __restrict__ Fb1,
                                                const float* __restrict__ bscale,
                                                float* __restrict__ loc, int G) {
    __shared__ float Xs[64][68];
    __shared__ float Ws[64][64];
    __shared__ float bs[64];
    const int tid = threadIdx.x;
    const int tc = tid & 15;
    const int tr = tid >> 4;
    const int r0 = blockIdx.x * 64;
    const int c0 = blockIdx.y * 64;

    for (int i = tid; i < 4096; i += 256)
        Ws[i >> 6][i & 63] = FW1[(size_t)(i >> 6) * 128 + c0 + (i & 63)];
    if (tid < 64) bs[tid] = Fb1[c0 + tid];
#pragma unroll
    for (int p = 0; p < 4; p++) {
        int row = p * 16 + (tid >> 4);
        int col = (tid & 15) * 4;
        float4 v = make_float4(0.f, 0.f, 0.f, 0.f);
        if (r0 + row < G) v = *(const float4*)&M[(size_t)(r0 + row) * 64 + col];
        *(float4*)&Xs[row][col] = v;
    }
    __syncthreads();

    float acc[4][4];
#pragma unroll
    for (int i = 0; i < 4; i++)
#pragma unroll
        for (int j = 0; j < 4; j++) acc[i][j] = 0.f;

#pragma unroll 8
    for (int k = 0; k < 64; k++) {
        float4 wv = *(const float4*)&Ws[k][tc * 4];
        float x0 = Xs[tr * 4 + 0][k];
        float x1 = Xs[tr * 4 + 1][k];
        float x2 = Xs[tr * 4 + 2][k];
        float x3 = Xs[tr * 4 + 3][k];
        acc[0][0] += x0 * wv.x; acc[0][1] += x0 * wv.y; acc[0][2] += x0 * wv.z; acc[0][3] += x0 * wv.w;
        acc[1][0] += x1 * wv.x; acc[1][1] += x1 * wv.y; acc[1][2] += x1 * wv.z; acc[1][3] += x1 * wv.w;
        acc[2][0] += x2 * wv.x; acc[2][1] += x2 * wv.y; acc[2][2] += x2 * wv.z; acc[2][3] += x2 * wv.w;
        acc[3][0] += x3 * wv.x; acc[3][1] += x3 * wv.y; acc[3][2] += x3 * wv.z; acc[3][3] += x3 * wv.w;
    }

#pragma unroll
    for (int i = 0; i < 4; i++) {
        int row = r0 + tr * 4 + i;
        if (row >= G) continue;
        float sc = bscale[row];
        float4 o;
        o.x = acc[i][0] + sc * bs[tc * 4 + 0];
        o.y = acc[i][1] + sc * bs[tc * 4 + 1];
        o.z = acc[i][2] + sc * bs[tc * 4 + 2];
        o.w = acc[i][3] + sc * bs[tc * 4 + 3];
        *(float4*)&loc[(size_t)row * 128 + c0 + tc * 4] = o;
    }
}

// ic = loc @ FW2 + Fb2; thread 0 also writes the trailing scalar 0.
__global__ __launch_bounds__(256) void ic_kernel(const float* __restrict__ loc,
                                                 const float* __restrict__ FW2,
                                                 const float* __restrict__ Fb2,
                                                 float* __restrict__ ic,
                                                 float* __restrict__ scalar_out, int G) {
    __shared__ float Ws[1280];
    __shared__ float bs[10];
    for (int i = threadIdx.x; i < 1280; i += 256) Ws[i] = FW2[i];
    if (threadIdx.x < 10) bs[threadIdx.x] = Fb2[threadIdx.x];
    __syncthreads();
    int g = blockIdx.x * 256 + threadIdx.x;
    if (g == 0) scalar_out[0] = 0.f;
    if (g >= G) return;
    float acc[10];
#pragma unroll
    for (int j = 0; j < 10; j++) acc[j] = bs[j];
    const float* xr = loc + (size_t)g * 128;
    for (int k = 0; k < 128; k++) {
        float xv = xr[k];
#pragma unroll
        for (int j = 0; j < 10; j++) acc[j] += xv * Ws[k * 10 + j];
    }
    float* o = ic + (size_t)g * 10;
#pragma unroll
    for (int j = 0; j < 10; j++) o[j] = acc[j];
}

// ZW = (X @ W) * dinv[row]  [G x 128 @ 128 x 128]; 64x64 tile (grid.y = 2 col tiles).
__global__ __launch_bounds__(256) void gemm_g128(const float* __restrict__ X,
                                                 const float* __restrict__ W,
                                                 const float* __restrict__ dinv,
                                                 float* __restrict__ ZW, int G) {
    __shared__ float Xs[64][68];
    __shared__ float Ws[64][64];
    const int tid = threadIdx.x;
    const int tc = tid & 15;
    const int tr = tid >> 4;
    const int r0 = blockIdx.x * 64;
    const int c0 = blockIdx.y * 64;

    float acc[4][4];
#pragma unroll
    for (int i = 0; i < 4; i++)
#pragma unroll
        for (int j = 0; j < 4; j++) acc[i][j] = 0.f;

    for (int kc = 0; kc < 2; kc++) {
        __syncthreads();
        for (int i = tid; i < 4096; i += 256)
            Ws[i >> 6][i & 63] = W[(size_t)(kc * 64 + (i >> 6)) * 128 + c0 + (i & 63)];
#pragma unroll
        for (int p = 0; p < 4; p++) {
            int row = p * 16 + (tid >> 4);
            int col = (tid & 15) * 4;
            float4 v = make_float4(0.f, 0.f, 0.f, 0.f);
            if (r0 + row < G) v = *(const float4*)&X[(size_t)(r0 + row) * 128 + kc * 64 + col];
            *(float4*)&Xs[row][col] = v;
        }
        __syncthreads();
#pragma unroll 8
        for (int k = 0; k < 64; k++) {
            float4 wv = *(const float4*)&Ws[k][tc * 4];
            float x0 = Xs[tr * 4 + 0][k];
            float x1 = Xs[tr * 4 + 1][k];
            float x2 = Xs[tr * 4 + 2][k];
            float x3 = Xs[tr * 4 + 3][k];
            acc[0][0] += x0 * wv.x; acc[0][1] += x0 * wv.y; acc[0][2] += x0 * wv.z; acc[0][3] += x0 * wv.w;
            acc[1][0] += x1 * wv.x; acc[1][1] += x1 * wv.y; acc[1][2] += x1 * wv.z; acc[1][3] += x1 * wv.w;
            acc[2][0] += x2 * wv.x; acc[2][1] += x2 * wv.y; acc[2][2] += x2 * wv.z; acc[2][3] += x2 * wv.w;
            acc[3][0] += x3 * wv.x; acc[3][1] += x3 * wv.y; acc[3][2] += x3 * wv.z; acc[3][3] += x3 * wv.w;
        }
    }

#pragma unroll
    for (int i = 0; i < 4; i++) {
        int row = r0 + tr * 4 + i;
        if (row >= G) continue;
        float dv = dinv[row];
        *(float4*)&ZW[(size_t)row * 128 + c0 + tc * 4] =
            make_float4(acc[i][0] * dv, acc[i][1] * dv, acc[i][2] * dv, acc[i][3] * dv);
    }
}

// ZW = X @ W [G x 128 @ 128 x 10]; HC = ZW*mdrecip + bias
__global__ __launch_bounds__(256) void gemm_g10(const float* __restrict__ X,
                                                const float* __restrict__ W,
                                                const float* __restrict__ bias,
                                                const float* __restrict__ mdrecip,
                                                float* __restrict__ ZW,
                                                float* __restrict__ HC, int G) {
    __shared__ float Ws[1280];
    __shared__ float bs[10];
    for (int i = threadIdx.x; i < 1280; i += 256) Ws[i] = W[i];
    if (threadIdx.x < 10) bs[threadIdx.x] = bias[threadIdx.x];
    __syncthreads();
    int g = blockIdx.x * 256 + threadIdx.x;
    if (g >= G) return;
    float acc[10];
#pragma unroll
    for (int j = 0; j < 10; j++) acc[j] = 0.f;
    const float4* xr = (const float4*)(X + (size_t)g * 128);
#pragma unroll 4
    for (int k4 = 0; k4 < 32; k4++) {
        float4 v = xr[k4];
        float xv[4] = {v.x, v.y, v.z, v.w};
#pragma unroll
        for (int d = 0; d < 4; d++) {
            float xs = xv[d];
            int k = k4 * 4 + d;
#pragma unroll
            for (int j = 0; j < 10; j++) acc[j] += xs * Ws[k * 10 + j];
        }
    }
    float dr = mdrecip[g];
    float* zw = ZW + (size_t)g * 10;
    float* hc = HC + (size_t)g * 10;
#pragma unroll
    for (int j = 0; j < 10; j++) {
        zw[j] = acc[j];
        hc[j] = acc[j] * dr + bs[j];
    }
}

// HC[md] += ZW[ms] * mdinv[ms]*mdinv[md]  (10 features, tiny)
__global__ void edge_agg10(const int* __restrict__ ms, const int* __restrict__ md,
                           const float* __restrict__ mdinv, const float* __restrict__ ZW,
                           float* __restrict__ HC, int EM) {
    int e = blockIdx.x * blockDim.x + threadIdx.x;
    if (e >= EM) return;
    int s = ms[e], d = md[e];
    float w = mdinv[s] * mdinv[d];
    const float* zr = ZW + (size_t)s * 10;
    float* out = HC + (size_t)d * 10;
#pragma unroll
    for (int j = 0; j < 10; j++) atomicAdd(out + j, zr[j] * w);
}

extern "C" void kernel_launch(void* const* d_in, const int* in_sizes, int n_in,
                              void* d_out, int out_size, void* d_ws, size_t ws_size,
                              hipStream_t stream) {
    const float* x    = (const float*)d_in[0];
    const int*   ei   = (const int*)d_in[1];
    const int*   batch= (const int*)d_in[2];
    const int*   me   = (const int*)d_in[3];
    const float* W1   = (const float*)d_in[5];
    const float* b1   = (const float*)d_in[6];
    const float* W2   = (const float*)d_in[7];
    const float* b2   = (const float*)d_in[8];
    const float* FW1  = (const float*)d_in[9];
    const float* Fb1  = (const float*)d_in[10];
    const float* FW2  = (const float*)d_in[11];
    const float* Fb2  = (const float*)d_in[12];
    const float* MW1  = (const float*)d_in[13];
    const float* mb1  = (const float*)d_in[14];
    const float* g1   = (const float*)d_in[15];
    const float* be1  = (const float*)d_in[16];
    const float* m1   = (const float*)d_in[17];
    const float* v1   = (const float*)d_in[18];
    const float* MW2  = (const float*)d_in[19];
    const float* mb2  = (const float*)d_in[20];
    const float* g2   = (const float*)d_in[21];
    const float* be2  = (const float*)d_in[22];
    const float* m2   = (const float*)d_in[23];
    const float* v2   = (const float*)d_in[24];
    const float* MW3  = (const float*)d_in[25];
    const float* mb3  = (const float*)d_in[26];

    const int N  = in_sizes[0] / 64;
    const int E  = in_sizes[1] / 2;
    const int EM = in_sizes[3] / 2;
    const int G  = (out_size - 1) / 276;

    float* out    = (float*)d_out;
    float* hc     = out;
    float* ic     = out + (size_t)G * 10;
    float* loc    = out + (size_t)G * 20;
    float* glob   = out + (size_t)G * 20 + (size_t)G * 128;
    float* scalar = out + (size_t)G * 276;

    char*  ws  = (char*)d_ws;
    size_t off = 0;
    auto alloc = [&](size_t bytes) -> void* {
        void* p = (void*)(ws + off);
        off += (bytes + 255) & ~(size_t)255;
        return p;
    };
    int*   hist    = (int*)alloc((size_t)(N + 1) * 4);
    int*   rowptr  = (int*)alloc((size_t)(N + 1) * 4);
    int*   cursor  = (int*)alloc((size_t)N * 4);
    int*   bsum    = (int*)alloc(512 * 4);
    int*   col     = (int*)alloc((size_t)E * 4);
    float* dinv    = (float*)alloc((size_t)N * 4);
    float* drecip  = (float*)alloc((size_t)N * 4);
    int*   mhist   = (int*)alloc((size_t)(G + 1) * 4);
    int*   mrowptr = (int*)alloc((size_t)(G + 1) * 4);
    int*   mcursor = (int*)alloc((size_t)G * 4);
    int*   mbsum   = (int*)alloc(512 * 4);
    int*   mcol    = (int*)alloc((size_t)EM * 4);
    float* mdinv   = (float*)alloc((size_t)G * 4);
    float* mdrecip = (float*)alloc((size_t)G * 4);
    float* A       = (float*)alloc((size_t)N * 64 * 4);   // xw1 * dinv
    float* A2      = (float*)alloc((size_t)N * 64 * 4);   // xw2 * dinv
    float* M       = (float*)alloc((size_t)G * 64 * 4);   // segment means
    float* bscale  = (float*)alloc((size_t)G * 4);
    float* mzw     = (float*)alloc((size_t)G * 128 * 4);
    float* z1      = (float*)alloc((size_t)G * 128 * 4);
    float* zw3     = (float*)alloc((size_t)G * 10 * 4);
    (void)ws_size;

    const int* src = ei;
    const int* dst = ei + E;
    const int* ms  = me;
    const int* md  = me + EM;

    // ---- degrees + CSR build (node graph and macro graph) ----
    hipMemsetAsync(hist, 0, (size_t)(N + 1) * 4, stream);
    hipMemsetAsync(mhist, 0, (size_t)(G + 1) * 4, stream);
    hist_kernel<<<(E + 255) / 256, 256, 0, stream>>>(dst, hist, E);
    hist_kernel<<<(EM + 255) / 256, 256, 0, stream>>>(md, mhist, EM);
    finalize_deg<<<(N + 255) / 256, 256, 0, stream>>>(hist, dinv, drecip, N);
    finalize_deg<<<(G + 255) / 256, 256, 0, stream>>>(mhist, mdinv, mdrecip, G);

    const int nb1 = (N + 1023) / 1024;
    scan1<<<nb1, 256, 0, stream>>>(hist, rowptr, bsum, N);
    scan2<<<1, 512, 0, stream>>>(bsum, nb1);
    scan3<<<(N + 255) / 256, 256, 0, stream>>>(rowptr, bsum, cursor, N, E);
    const int nb2 = (G + 1023) / 1024;
    scan1<<<nb2, 256, 0, stream>>>(mhist, mrowptr, mbsum, G);
    scan2<<<1, 512, 0, stream>>>(mbsum, nb2);
    scan3<<<(G + 255) / 256, 256, 0, stream>>>(mrowptr, mbsum, mcursor, G, EM);

    {
        const int nchunks = 2048;
        const int per_chunk = (E + nchunks - 1) / nchunks;
        const int npx = (N + 7) / 8;
        scatter_xcd<<<nchunks * 8, 256, 0, stream>>>(src, dst, cursor, col, E, per_chunk, npx);
    }
    scatter_kernel<<<(EM + 255) / 256, 256, 0, stream>>>(ms, md, mcursor, mcol, EM);

    const int nblk = (N + 63) / 64;

    // Layer 1 GEMM (x streamed NT)
    gemm_n64<<<nblk, 256, 0, stream>>>(x, W1, dinv, A, N);
    // Layer 2 GEMM with fused layer-1 aggregation; A2 stored NT
    gemm_agg_n64<<<nblk, 256, 0, stream>>>(rowptr, col, A, b1, W2, dinv, A2, N);
    // Pooling with fused layer-2 aggregation (4 node-parallel groups)
    segmean_agg<<<G, 256, 0, stream>>>(rowptr, col, A2, b2, dinv, batch, M, bscale, N);
    {
        dim3 lg((G + 63) / 64, 2);
        loc_gemm<<<lg, 256, 0, stream>>>(M, FW1, Fb1, bscale, loc, G);
    }
    ic_kernel<<<(G + 255) / 256, 256, 0, stream>>>(loc, FW2, Fb2, ic, scalar, G);

    dim3 mg((G + 63) / 64, 2);

    // Macro layer 1 (agg + BN + relu fused)
    gemm_g128<<<mg, 256, 0, stream>>>(loc, MW1, mdinv, mzw, G);
    csr_agg_bn128<<<(G * 32 + 255) / 256, 256, 0, stream>>>(mrowptr, mcol, mzw, mb1, mdinv,
                                                            g1, be1, m1, v1, z1, G);
    // Macro layer 2 -> glob (in d_out)
    gemm_g128<<<mg, 256, 0, stream>>>(z1, MW2, mdinv, mzw, G);
    csr_agg_bn128<<<(G * 32 + 255) / 256, 256, 0, stream>>>(mrowptr, mcol, mzw, mb2, mdinv,
                                                            g2, be2, m2, v2, glob, G);

    // hc = GCN(glob, MW3, mb3)
    gemm_g10<<<(G + 255) / 256, 256, 0, stream>>>(glob, MW3, mb3, mdrecip, zw3, hc, G);
    edge_agg10<<<(EM + 255) / 256, 256, 0, stream>>>(ms, md, mdinv, zw3, hc, EM);
}

// Round 10
// 800.558 us; speedup vs baseline: 1.1514x; 1.1514x over previous
//
#include <hip/hip_runtime.h>
#include <hip/hip_fp16.h>

// ---------------------------------------------------------------------------
// SEAL GNN pipeline.
// R10: gather payload halved — A/A2 (inter-layer node features) stored fp16,
// all accumulation fp32. The two edge-gather passes are traffic-bound
// (~380 MB FETCH each, invariant to occupancy/NT per R7-R9); fp16 rows cut
// per-edge bytes 256->128 and footprint 128->64 MB. segmean_agg reverted to
// the 64-thread form (R9's 4-way split regressed it 188->240 us).
// ---------------------------------------------------------------------------

typedef float nf4 __attribute__((ext_vector_type(4)));
struct __align__(8) h4 { __half2 a, b; };

__global__ void hist_kernel(const int* __restrict__ dst, int* __restrict__ hist, int E) {
    int e = blockIdx.x * blockDim.x + threadIdx.x;
    if (e < E) atomicAdd(&hist[dst[e]], 1);
}

__global__ void finalize_deg(const int* __restrict__ hist, float* __restrict__ dinv,
                             float* __restrict__ drecip, int n) {
    int i = blockIdx.x * blockDim.x + threadIdx.x;
    if (i < n) {
        float c = (float)hist[i] + 1.0f;   // self-loop included
        dinv[i]   = rsqrtf(c);
        drecip[i] = 1.0f / c;
    }
}

// Exclusive scan, stage 1: 1024 counts per 256-thread block.
__global__ __launch_bounds__(256) void scan1(const int* __restrict__ cnt, int* __restrict__ pre,
                                             int* __restrict__ bsum, int n) {
    __shared__ int s[256];
    int base = blockIdx.x * 1024;
    int t = threadIdx.x;
    int v[4];
    int loc = 0;
#pragma unroll
    for (int j = 0; j < 4; j++) {
        int i = base + t * 4 + j;
        v[j] = (i < n) ? cnt[i] : 0;
        loc += v[j];
    }
    s[t] = loc;
    __syncthreads();
    for (int off = 1; off < 256; off <<= 1) {
        int x = (t >= off) ? s[t - off] : 0;
        __syncthreads();
        s[t] += x;
        __syncthreads();
    }
    int run = s[t] - loc;
    if (t == 255) bsum[blockIdx.x] = s[255];
#pragma unroll
    for (int j = 0; j < 4; j++) {
        int i = base + t * 4 + j;
        if (i < n) pre[i] = run;
        run += v[j];
    }
}

// Stage 2: exclusive scan of block sums in place (nb <= 512).
__global__ __launch_bounds__(512) void scan2(int* __restrict__ bsum, int nb) {
    __shared__ int s[512];
    int t = threadIdx.x;
    int v = (t < nb) ? bsum[t] : 0;
    s[t] = v;
    __syncthreads();
    for (int off = 1; off < 512; off <<= 1) {
        int x = (t >= off) ? s[t - off] : 0;
        __syncthreads();
        s[t] += x;
        __syncthreads();
    }
    if (t < nb) bsum[t] = s[t] - v;
}

// Stage 3: add block offsets; also initializes cursor; writes rowptr[n] = E.
__global__ void scan3(int* __restrict__ pre, const int* __restrict__ bsum,
                      int* __restrict__ cursor, int n, int E) {
    int i = blockIdx.x * blockDim.x + threadIdx.x;
    if (i < n) {
        int v = pre[i] + bsum[i >> 10];
        pre[i] = v;
        cursor[i] = v;
    }
    if (i == 0) pre[n] = E;
}

// XCD-bucketed scatter (see R6 comment).
__global__ __launch_bounds__(256) void scatter_xcd(const int* __restrict__ src,
                                                   const int* __restrict__ dst,
                                                   int* __restrict__ cursor,
                                                   int* __restrict__ col,
                                                   int E, int per_chunk, int npx) {
    int bucket = blockIdx.x & 7;
    int chunk  = blockIdx.x >> 3;
    int lo = bucket * npx;
    int hi = lo + npx;
    int e0 = chunk * per_chunk;
    int e1 = min(e0 + per_chunk, E);
    for (int e = e0 + threadIdx.x; e < e1; e += 256) {
        int d = dst[e];
        if (d < lo || d >= hi) continue;
        int p = atomicAdd(&cursor[d], 1);
        col[p] = src[e];
    }
}

// Simple scatter for the tiny macro graph.
__global__ void scatter_kernel(const int* __restrict__ src, const int* __restrict__ dst,
                               int* __restrict__ cursor, int* __restrict__ col, int E) {
    int e = blockIdx.x * blockDim.x + threadIdx.x;
    if (e >= E) return;
    int p = atomicAdd(&cursor[dst[e]], 1);
    col[p] = src[e];
}

// Macro aggregation with fused BatchNorm(eval)+ReLU (fp32, tiny).
__global__ __launch_bounds__(256) void csr_agg_bn128(const int* __restrict__ rowptr,
                                                     const int* __restrict__ col,
                                                     const float* __restrict__ A,
                                                     const float* __restrict__ bias,
                                                     const float* __restrict__ dinv,
                                                     const float* __restrict__ gam,
                                                     const float* __restrict__ bet,
                                                     const float* __restrict__ mean,
                                                     const float* __restrict__ var,
                                                     float* __restrict__ Z, int N) {
    constexpr int F = 128, TPN = 32, NPB = 8;
    int node = blockIdx.x * NPB + threadIdx.x / TPN;
    int lane = threadIdx.x % TPN;
    if (node >= N) return;
    int c = lane * 4;
    float4 acc = *(const float4*)&A[(size_t)node * F + c];
    int e0 = rowptr[node], e1 = rowptr[node + 1];
    int e = e0;
    for (; e + 4 <= e1; e += 4) {
        int s0 = col[e + 0], s1 = col[e + 1], s2 = col[e + 2], s3 = col[e + 3];
        float4 v0 = *(const float4*)&A[(size_t)s0 * F + c];
        float4 v1 = *(const float4*)&A[(size_t)s1 * F + c];
        float4 v2 = *(const float4*)&A[(size_t)s2 * F + c];
        float4 v3 = *(const float4*)&A[(size_t)s3 * F + c];
        acc.x += v0.x + v1.x + v2.x + v3.x;
        acc.y += v0.y + v1.y + v2.y + v3.y;
        acc.z += v0.z + v1.z + v2.z + v3.z;
        acc.w += v0.w + v1.w + v2.w + v3.w;
    }
    for (; e < e1; e++) {
        int s = col[e];
        float4 v = *(const float4*)&A[(size_t)s * F + c];
        acc.x += v.x; acc.y += v.y; acc.z += v.z; acc.w += v.w;
    }
    float dv = dinv[node];
    float4 b4 = *(const float4*)&bias[c];
    float4 g4 = *(const float4*)&gam[c];
    float4 be4 = *(const float4*)&bet[c];
    float4 m4 = *(const float4*)&mean[c];
    float4 v4 = *(const float4*)&var[c];
    float4 o;
    o.x = fmaxf((acc.x * dv + b4.x - m4.x) * rsqrtf(v4.x + 1e-5f) * g4.x + be4.x, 0.f);
    o.y = fmaxf((acc.y * dv + b4.y - m4.y) * rsqrtf(v4.y + 1e-5f) * g4.y + be4.y, 0.f);
    o.z = fmaxf((acc.z * dv + b4.z - m4.z) * rsqrtf(v4.z + 1e-5f) * g4.z + be4.z, 0.f);
    o.w = fmaxf((acc.w * dv + b4.w - m4.w) * rsqrtf(v4.w + 1e-5f) * g4.w + be4.w, 0.f);
    *(float4*)&Z[(size_t)node * F + c] = o;
}

// Layer-1 GEMM: A_h = fp16( (X @ W1) * dinv[row] ). W from global (L1-resident).
__global__ __launch_bounds__(256) void gemm_n64(const float* __restrict__ X,
                                                const float* __restrict__ W,
                                                const float* __restrict__ dinv,
                                                __half* __restrict__ XW, int N) {
    __shared__ float Xs[64][68];
    const int tid = threadIdx.x;
    const int tc = tid & 15;
    const int tr = tid >> 4;
    const int r0 = blockIdx.x * 64;

#pragma unroll
    for (int p = 0; p < 4; p++) {
        int row = p * 16 + (tid >> 4);
        int col = (tid & 15) * 4;
        float4 v = make_float4(0.f, 0.f, 0.f, 0.f);
        if (r0 + row < N) {
            nf4 nv = __builtin_nontemporal_load((const nf4*)&X[(size_t)(r0 + row) * 64 + col]);
            v = make_float4(nv.x, nv.y, nv.z, nv.w);
        }
        *(float4*)&Xs[row][col] = v;
    }
    __syncthreads();

    float acc[4][4];
#pragma unroll
    for (int i = 0; i < 4; i++)
#pragma unroll
        for (int j = 0; j < 4; j++) acc[i][j] = 0.f;

    const float* wp = W + tc * 4;
#pragma unroll 8
    for (int k = 0; k < 64; k++) {
        float4 wv = *(const float4*)&wp[k * 64];
        float x0 = Xs[tr * 4 + 0][k];
        float x1 = Xs[tr * 4 + 1][k];
        float x2 = Xs[tr * 4 + 2][k];
        float x3 = Xs[tr * 4 + 3][k];
        acc[0][0] += x0 * wv.x; acc[0][1] += x0 * wv.y; acc[0][2] += x0 * wv.z; acc[0][3] += x0 * wv.w;
        acc[1][0] += x1 * wv.x; acc[1][1] += x1 * wv.y; acc[1][2] += x1 * wv.z; acc[1][3] += x1 * wv.w;
        acc[2][0] += x2 * wv.x; acc[2][1] += x2 * wv.y; acc[2][2] += x2 * wv.z; acc[2][3] += x2 * wv.w;
        acc[3][0] += x3 * wv.x; acc[3][1] += x3 * wv.y; acc[3][2] += x3 * wv.z; acc[3][3] += x3 * wv.w;
    }

#pragma unroll
    for (int i = 0; i < 4; i++) {
        int row = r0 + tr * 4 + i;
        if (row >= N) continue;
        float dv = dinv[row];
        h4 o;
        o.a = __floats2half2_rn(acc[i][0] * dv, acc[i][1] * dv);
        o.b = __floats2half2_rn(acc[i][2] * dv, acc[i][3] * dv);
        *(h4*)&XW[(size_t)row * 64 + tc * 4] = o;
    }
}

// Layer-2 fused: X-tile = relu(dinv*(A[row]+sum A[col]) + b_prev) into LDS
// (gathering fp16 rows, fp32 accumulate), then A2_h = fp16((Xs@W2)*dinv[row]).
__global__ __launch_bounds__(256) void gemm_agg_n64(const int* __restrict__ rowptr,
                                                    const int* __restrict__ col,
                                                    const __half* __restrict__ A,
                                                    const float* __restrict__ b_prev,
                                                    const float* __restrict__ W,
                                                    const float* __restrict__ dinv,
                                                    __half* __restrict__ XW, int N) {
    __shared__ float Xs[64][68];
    const int tid = threadIdx.x;
    const int tc = tid & 15;
    const int tr = tid >> 4;
    const int r0 = blockIdx.x * 64;

#pragma unroll
    for (int p = 0; p < 4; p++) {
        int row = p * 16 + (tid >> 4);
        int node = r0 + row;
        int c = (tid & 15) * 4;
        float4 acc = make_float4(0.f, 0.f, 0.f, 0.f);
        if (node < N) {
            h4 sv = *(const h4*)&A[(size_t)node * 64 + c];
            float2 f0 = __half22float2(sv.a);
            float2 f1 = __half22float2(sv.b);
            acc = make_float4(f0.x, f0.y, f1.x, f1.y);
            int e0 = rowptr[node], e1 = rowptr[node + 1];
            int e = e0;
            for (; e + 4 <= e1; e += 4) {
                int s0 = col[e + 0], s1 = col[e + 1], s2 = col[e + 2], s3 = col[e + 3];
                h4 v0 = *(const h4*)&A[(size_t)s0 * 64 + c];
                h4 v1 = *(const h4*)&A[(size_t)s1 * 64 + c];
                h4 v2 = *(const h4*)&A[(size_t)s2 * 64 + c];
                h4 v3 = *(const h4*)&A[(size_t)s3 * 64 + c];
                float2 a0 = __half22float2(v0.a), b0 = __half22float2(v0.b);
                float2 a1 = __half22float2(v1.a), b1 = __half22float2(v1.b);
                float2 a2 = __half22float2(v2.a), b2 = __half22float2(v2.b);
                float2 a3 = __half22float2(v3.a), b3 = __half22float2(v3.b);
                acc.x += a0.x + a1.x + a2.x + a3.x;
                acc.y += a0.y + a1.y + a2.y + a3.y;
                acc.z += b0.x + b1.x + b2.x + b3.x;
                acc.w += b0.y + b1.y + b2.y + b3.y;
            }
            for (; e < e1; e++) {
                int s = col[e];
                h4 v = *(const h4*)&A[(size_t)s * 64 + c];
                float2 a = __half22float2(v.a), b = __half22float2(v.b);
                acc.x += a.x; acc.y += a.y; acc.z += b.x; acc.w += b.y;
            }
            float dv = dinv[node];
            float4 b4 = *(const float4*)&b_prev[c];
            acc.x = fmaxf(acc.x * dv + b4.x, 0.f);
            acc.y = fmaxf(acc.y * dv + b4.y, 0.f);
            acc.z = fmaxf(acc.z * dv + b4.z, 0.f);
            acc.w = fmaxf(acc.w * dv + b4.w, 0.f);
        }
        *(float4*)&Xs[row][c] = acc;
    }
    __syncthreads();

    float acc[4][4];
#pragma unroll
    for (int i = 0; i < 4; i++)
#pragma unroll
        for (int j = 0; j < 4; j++) acc[i][j] = 0.f;

    const float* wp = W + tc * 4;
#pragma unroll 8
    for (int k = 0; k < 64; k++) {
        float4 wv = *(const float4*)&wp[k * 64];
        float x0 = Xs[tr * 4 + 0][k];
        float x1 = Xs[tr * 4 + 1][k];
        float x2 = Xs[tr * 4 + 2][k];
        float x3 = Xs[tr * 4 + 3][k];
        acc[0][0] += x0 * wv.x; acc[0][1] += x0 * wv.y; acc[0][2] += x0 * wv.z; acc[0][3] += x0 * wv.w;
        acc[1][0] += x1 * wv.x; acc[1][1] += x1 * wv.y; acc[1][2] += x1 * wv.z; acc[1][3] += x1 * wv.w;
        acc[2][0] += x2 * wv.x; acc[2][1] += x2 * wv.y; acc[2][2] += x2 * wv.z; acc[2][3] += x2 * wv.w;
        acc[3][0] += x3 * wv.x; acc[3][1] += x3 * wv.y; acc[3][2] += x3 * wv.z; acc[3][3] += x3 * wv.w;
    }

#pragma unroll
    for (int i = 0; i < 4; i++) {
        int row = r0 + tr * 4 + i;
        if (row >= N) continue;
        float dv = dinv[row];
        h4 o;
        o.a = __floats2half2_rn(acc[i][0] * dv, acc[i][1] * dv);
        o.b = __floats2half2_rn(acc[i][2] * dv, acc[i][3] * dv);
        *(h4*)&XW[(size_t)row * 64 + tc * 4] = o;
    }
}

// Pooling fused with layer-2 aggregation (64-thread form; fp16 gathers).
__global__ __launch_bounds__(64) void segmean_agg(const int* __restrict__ rowptr,
                                                  const int* __restrict__ col,
                                                  const __half* __restrict__ A2,
                                                  const float* __restrict__ b2,
                                                  const float* __restrict__ dinv,
                                                  const int* __restrict__ batch,
                                                  float* __restrict__ M,
                                                  float* __restrict__ bscale, int N) {
    int g = blockIdx.x;
    int t = threadIdx.x;   // feature column 0..63
    int lo = 0, hi = N;
    while (lo < hi) { int m = (lo + hi) >> 1; if (batch[m] < g) lo = m + 1; else hi = m; }
    int start = lo;
    hi = N;
    while (lo < hi) { int m = (lo + hi) >> 1; if (batch[m] < g + 1) lo = m + 1; else hi = m; }
    int end = lo;

    float bb = b2[t];
    float msum = 0.f;
    for (int node = start; node < end; node++) {
        float acc = __half2float(A2[(size_t)node * 64 + t]);
        int e0 = rowptr[node], e1 = rowptr[node + 1];
        int e = e0;
        for (; e + 4 <= e1; e += 4) {
            int s0 = col[e + 0], s1 = col[e + 1], s2 = col[e + 2], s3 = col[e + 3];
            acc += __half2float(A2[(size_t)s0 * 64 + t]) + __half2float(A2[(size_t)s1 * 64 + t])
                 + __half2float(A2[(size_t)s2 * 64 + t]) + __half2float(A2[(size_t)s3 * 64 + t]);
        }
        for (; e < e1; e++) acc += __half2float(A2[(size_t)col[e] * 64 + t]);
        msum += fmaxf(acc * dinv[node] + bb, 0.f);
    }
    int cnt = end - start;
    float inv = (cnt > 0) ? 1.f / (float)cnt : 0.f;
    M[(size_t)g * 64 + t] = msum * inv;
    if (t == 0) bscale[g] = (cnt > 0) ? 1.f : 0.f;
}

// loc = M @ FW1 + bscale*Fb1   [G x 64 @ 64 x 128]; grid.y = 2 col-tiles.
__global__ __launch_bounds__(256) void loc_gemm(const float* __restrict__ M,
                                                const float* __restrict__ FW1,
                                                const float* __restrict__ Fb1,
                                                const float* __restrict__ bscale,
                                                float* __restrict__ loc, int G) {
    __shared__ float Xs[64][68];
    __shared__ float Ws[64][64];
    __shared__ float bs[64];
    const int tid = threadIdx.x;
    const int tc = tid & 15;
    const int tr = tid >> 4;
    const int r0 = blockIdx.x * 64;
    const int c0 = blockIdx.y * 64;

    for (int i = tid; i < 4096; i += 256)
        Ws[i >> 6][i & 63] = FW1[(size_t)(i >> 6) * 128 + c0 + (i & 63)];
    if (tid < 64) bs[tid] = Fb1[c0 + tid];
#pragma unroll
    for (int p = 0; p < 4; p++) {
        int row = p * 16 + (tid >> 4);
        int col = (tid & 15) * 4;
        float4 v = make_float4(0.f, 0.f, 0.f, 0.f);
        if (r0 + row < G) v = *(const float4*)&M[(size_t)(r0 + row) * 64 + col];
        *(float4*)&Xs[row][col] = v;
    }
    __syncthreads();

    float acc[4][4];
#pragma unroll
    for (int i = 0; i < 4; i++)
#pragma unroll
        for (int j = 0; j < 4; j++) acc[i][j] = 0.f;

#pragma unroll 8
    for (int k = 0; k < 64; k++) {
        float4 wv = *(const float4*)&Ws[k][tc * 4];
        float x0 = Xs[tr * 4 + 0][k];
        float x1 = Xs[tr * 4 + 1][k];
        float x2 = Xs[tr * 4 + 2][k];
        float x3 = Xs[tr * 4 + 3][k];
        acc[0][0] += x0 * wv.x; acc[0][1] += x0 * wv.y; acc[0][2] += x0 * wv.z; acc[0][3] += x0 * wv.w;
        acc[1][0] += x1 * wv.x; acc[1][1] += x1 * wv.y; acc[1][2] += x1 * wv.z; acc[1][3] += x1 * wv.w;
        acc[2][0] += x2 * wv.x; acc[2][1] += x2 * wv.y; acc[2][2] += x2 * wv.z; acc[2][3] += x2 * wv.w;
        acc[3][0] += x3 * wv.x; acc[3][1] += x3 * wv.y; acc[3][2] += x3 * wv.z; acc[3][3] += x3 * wv.w;
    }

#pragma unroll
    for (int i = 0; i < 4; i++) {
        int row = r0 + tr * 4 + i;
        if (row >= G) continue;
        float sc = bscale[row];
        float4 o;
        o.x = acc[i][0] + sc * bs[tc * 4 + 0];
        o.y = acc[i][1] + sc * bs[tc * 4 + 1];
        o.z = acc[i][2] + sc * bs[tc * 4 + 2];
        o.w = acc[i][3] + sc * bs[tc * 4 + 3];
        *(float4*)&loc[(size_t)row * 128 + c0 + tc * 4] = o;
    }
}

// ic = loc @ FW2 + Fb2; thread 0 also writes the trailing scalar 0.
__global__ __launch_bounds__(256) void ic_kernel(const float* __restrict__ loc,
                                                 const float* __restrict__ FW2,
                                                 const float* __restrict__ Fb2,
                                                 float* __restrict__ ic,
                                                 float* __restrict__ scalar_out, int G) {
    __shared__ float Ws[1280];
    __shared__ float bs[10];
    for (int i = threadIdx.x; i < 1280; i += 256) Ws[i] = FW2[i];
    if (threadIdx.x < 10) bs[threadIdx.x] = Fb2[threadIdx.x];
    __syncthreads();
    int g = blockIdx.x * 256 + threadIdx.x;
    if (g == 0) scalar_out[0] = 0.f;
    if (g >= G) return;
    float acc[10];
#pragma unroll
    for (int j = 0; j < 10; j++) acc[j] = bs[j];
    const float* xr = loc + (size_t)g * 128;
    for (int k = 0; k < 128; k++) {
        float xv = xr[k];
#pragma unroll
        for (int j = 0; j < 10; j++) acc[j] += xv * Ws[k * 10 + j];
    }
    float* o = ic + (size_t)g * 10;
#pragma unroll
    for (int j = 0; j < 10; j++) o[j] = acc[j];
}

// ZW = (X @ W) * dinv[row]  [G x 128 @ 128 x 128]; 64x64 tile (grid.y = 2 col tiles).
__global__ __launch_bounds__(256) void gemm_g128(const float* __restrict__ X,
                                                 const float* __restrict__ W,
                                                 const float* __restrict__ dinv,
                                                 float* __restrict__ ZW, int G) {
    __shared__ float Xs[64][68];
    __shared__ float Ws[64][64];
    const int tid = threadIdx.x;
    const int tc = tid & 15;
    const int tr = tid >> 4;
    const int r0 = blockIdx.x * 64;
    const int c0 = blockIdx.y * 64;

    float acc[4][4];
#pragma unroll
    for (int i = 0; i < 4; i++)
#pragma unroll
        for (int j = 0; j < 4; j++) acc[i][j] = 0.f;

    for (int kc = 0; kc < 2; kc++) {
        __syncthreads();
        for (int i = tid; i < 4096; i += 256)
            Ws[i >> 6][i & 63] = W[(size_t)(kc * 64 + (i >> 6)) * 128 + c0 + (i & 63)];
#pragma unroll
        for (int p = 0; p < 4; p++) {
            int row = p * 16 + (tid >> 4);
            int col = (tid & 15) * 4;
            float4 v = make_float4(0.f, 0.f, 0.f, 0.f);
            if (r0 + row < G) v = *(const float4*)&X[(size_t)(r0 + row) * 128 + kc * 64 + col];
            *(float4*)&Xs[row][col] = v;
        }
        __syncthreads();
#pragma unroll 8
        for (int k = 0; k < 64; k++) {
            float4 wv = *(const float4*)&Ws[k][tc * 4];
            float x0 = Xs[tr * 4 + 0][k];
            float x1 = Xs[tr * 4 + 1][k];
            float x2 = Xs[tr * 4 + 2][k];
            float x3 = Xs[tr * 4 + 3][k];
            acc[0][0] += x0 * wv.x; acc[0][1] += x0 * wv.y; acc[0][2] += x0 * wv.z; acc[0][3] += x0 * wv.w;
            acc[1][0] += x1 * wv.x; acc[1][1] += x1 * wv.y; acc[1][2] += x1 * wv.z; acc[1][3] += x1 * wv.w;
            acc[2][0] += x2 * wv.x; acc[2][1] += x2 * wv.y; acc[2][2] += x2 * wv.z; acc[2][3] += x2 * wv.w;
            acc[3][0] += x3 * wv.x; acc[3][1] += x3 * wv.y; acc[3][2] += x3 * wv.z; acc[3][3] += x3 * wv.w;
        }
    }

#pragma unroll
    for (int i = 0; i < 4; i++) {
        int row = r0 + tr * 4 + i;
        if (row >= G) continue;
        float dv = dinv[row];
        *(float4*)&ZW[(size_t)row * 128 + c0 + tc * 4] =
            make_float4(acc[i][0] * dv, acc[i][1] * dv, acc[i][2] * dv, acc[i][3] * dv);
    }
}

// ZW = X @ W [G x 128 @ 128 x 10]; HC = ZW*mdrecip + bias
__global__ __launch_bounds__(256) void gemm_g10(const float* __restrict__ X,
                                                const float* __restrict__ W,
                                                const float* __restrict__ bias,
                                                const float* __restrict__ mdrecip,
                                                float* __restrict__ ZW,
                                                float* __restrict__ HC, int G) {
    __shared__ float Ws[1280];
    __shared__ float bs[10];
    for (int i = threadIdx.x; i < 1280; i += 256) Ws[i] = W[i];
    if (threadIdx.x < 10) bs[threadIdx.x] = bias[threadIdx.x];
    __syncthreads();
    int g = blockIdx.x * 256 + threadIdx.x;
    if (g >= G) return;
    float acc[10];
#pragma unroll
    for (int j = 0; j < 10; j++) acc[j] = 0.f;
    const float4* xr = (const float4*)(X + (size_t)g * 128);
#pragma unroll 4
    for (int k4 = 0; k4 < 32; k4++) {
        float4 v = xr[k4];
        float xv[4] = {v.x, v.y, v.z, v.w};
#pragma unroll
        for (int d = 0; d < 4; d++) {
            float xs = xv[d];
            int k = k4 * 4 + d;
#pragma unroll
            for (int j = 0; j < 10; j++) acc[j] += xs * Ws[k * 10 + j];
        }
    }
    float dr = mdrecip[g];
    float* zw = ZW + (size_t)g * 10;
    float* hc = HC + (size_t)g * 10;
#pragma unroll
    for (int j = 0; j < 10; j++) {
        zw[j] = acc[j];
        hc[j] = acc[j] * dr + bs[j];
    }
}

// HC[md] += ZW[ms] * mdinv[ms]*mdinv[md]  (10 features, tiny)
__global__ void edge_agg10(const int* __restrict__ ms, const int* __restrict__ md,
                           const float* __restrict__ mdinv, const float* __restrict__ ZW,
                           float* __restrict__ HC, int EM) {
    int e = blockIdx.x * blockDim.x + threadIdx.x;
    if (e >= EM) return;
    int s = ms[e], d = md[e];
    float w = mdinv[s] * mdinv[d];
    const float* zr = ZW + (size_t)s * 10;
    float* out = HC + (size_t)d * 10;
#pragma unroll
    for (int j = 0; j < 10; j++) atomicAdd(out + j, zr[j] * w);
}

extern "C" void kernel_launch(void* const* d_in, const int* in_sizes, int n_in,
                              void* d_out, int out_size, void* d_ws, size_t ws_size,
                              hipStream_t stream) {
    const float* x    = (const float*)d_in[0];
    const int*   ei   = (const int*)d_in[1];
    const int*   batch= (const int*)d_in[2];
    const int*   me   = (const int*)d_in[3];
    const float* W1   = (const float*)d_in[5];
    const float* b1   = (const float*)d_in[6];
    const float* W2   = (const float*)d_in[7];
    const float* b2   = (const float*)d_in[8];
    const float* FW1  = (const float*)d_in[9];
    const float* Fb1  = (const float*)d_in[10];
    const float* FW2  = (const float*)d_in[11];
    const float* Fb2  = (const float*)d_in[12];
    const float* MW1  = (const float*)d_in[13];
    const float* mb1  = (const float*)d_in[14];
    const float* g1   = (const float*)d_in[15];
    const float* be1  = (const float*)d_in[16];
    const float* m1   = (const float*)d_in[17];
    const float* v1   = (const float*)d_in[18];
    const float* MW2  = (const float*)d_in[19];
    const float* mb2  = (const float*)d_in[20];
    const float* g2   = (const float*)d_in[21];
    const float* be2  = (const float*)d_in[22];
    const float* m2   = (const float*)d_in[23];
    const float* v2   = (const float*)d_in[24];
    const float* MW3  = (const float*)d_in[25];
    const float* mb3  = (const float*)d_in[26];

    const int N  = in_sizes[0] / 64;
    const int E  = in_sizes[1] / 2;
    const int EM = in_sizes[3] / 2;
    const int G  = (out_size - 1) / 276;

    float* out    = (float*)d_out;
    float* hc     = out;
    float* ic     = out + (size_t)G * 10;
    float* loc    = out + (size_t)G * 20;
    float* glob   = out + (size_t)G * 20 + (size_t)G * 128;
    float* scalar = out + (size_t)G * 276;

    char*  ws  = (char*)d_ws;
    size_t off = 0;
    auto alloc = [&](size_t bytes) -> void* {
        void* p = (void*)(ws + off);
        off += (bytes + 255) & ~(size_t)255;
        return p;
    };
    int*    hist    = (int*)alloc((size_t)(N + 1) * 4);
    int*    rowptr  = (int*)alloc((size_t)(N + 1) * 4);
    int*    cursor  = (int*)alloc((size_t)N * 4);
    int*    bsum    = (int*)alloc(512 * 4);
    int*    col     = (int*)alloc((size_t)E * 4);
    float*  dinv    = (float*)alloc((size_t)N * 4);
    float*  drecip  = (float*)alloc((size_t)N * 4);
    int*    mhist   = (int*)alloc((size_t)(G + 1) * 4);
    int*    mrowptr = (int*)alloc((size_t)(G + 1) * 4);
    int*    mcursor = (int*)alloc((size_t)G * 4);
    int*    mbsum   = (int*)alloc(512 * 4);
    int*    mcol    = (int*)alloc((size_t)EM * 4);
    float*  mdinv   = (float*)alloc((size_t)G * 4);
    float*  mdrecip = (float*)alloc((size_t)G * 4);
    __half* A       = (__half*)alloc((size_t)N * 64 * 2);   // fp16 xw1*dinv
    __half* A2      = (__half*)alloc((size_t)N * 64 * 2);   // fp16 xw2*dinv
    float*  M       = (float*)alloc((size_t)G * 64 * 4);    // segment means
    float*  bscale  = (float*)alloc((size_t)G * 4);
    float*  mzw     = (float*)alloc((size_t)G * 128 * 4);
    float*  z1      = (float*)alloc((size_t)G * 128 * 4);
    float*  zw3     = (float*)alloc((size_t)G * 10 * 4);
    (void)ws_size;

    const int* src = ei;
    const int* dst = ei + E;
    const int* ms  = me;
    const int* md  = me + EM;

    // ---- degrees + CSR build (node graph and macro graph) ----
    hipMemsetAsync(hist, 0, (size_t)(N + 1) * 4, stream);
    hipMemsetAsync(mhist, 0, (size_t)(G + 1) * 4, stream);
    hist_kernel<<<(E + 255) / 256, 256, 0, stream>>>(dst, hist, E);
    hist_kernel<<<(EM + 255) / 256, 256, 0, stream>>>(md, mhist, EM);
    finalize_deg<<<(N + 255) / 256, 256, 0, stream>>>(hist, dinv, drecip, N);
    finalize_deg<<<(G + 255) / 256, 256, 0, stream>>>(mhist, mdinv, mdrecip, G);

    const int nb1 = (N + 1023) / 1024;
    scan1<<<nb1, 256, 0, stream>>>(hist, rowptr, bsum, N);
    scan2<<<1, 512, 0, stream>>>(bsum, nb1);
    scan3<<<(N + 255) / 256, 256, 0, stream>>>(rowptr, bsum, cursor, N, E);
    const int nb2 = (G + 1023) / 1024;
    scan1<<<nb2, 256, 0, stream>>>(mhist, mrowptr, mbsum, G);
    scan2<<<1, 512, 0, stream>>>(mbsum, nb2);
    scan3<<<(G + 255) / 256, 256, 0, stream>>>(mrowptr, mbsum, mcursor, G, EM);

    {
        const int nchunks = 2048;
        const int per_chunk = (E + nchunks - 1) / nchunks;
        const int npx = (N + 7) / 8;
        scatter_xcd<<<nchunks * 8, 256, 0, stream>>>(src, dst, cursor, col, E, per_chunk, npx);
    }
    scatter_kernel<<<(EM + 255) / 256, 256, 0, stream>>>(ms, md, mcursor, mcol, EM);

    const int nblk = (N + 63) / 64;

    // Layer 1 GEMM -> fp16 A
    gemm_n64<<<nblk, 256, 0, stream>>>(x, W1, dinv, A, N);
    // Layer 2 GEMM with fused layer-1 aggregation -> fp16 A2
    gemm_agg_n64<<<nblk, 256, 0, stream>>>(rowptr, col, A, b1, W2, dinv, A2, N);
    // Pooling with fused layer-2 aggregation
    segmean_agg<<<G, 64, 0, stream>>>(rowptr, col, A2, b2, dinv, batch, M, bscale, N);
    {
        dim3 lg((G + 63) / 64, 2);
        loc_gemm<<<lg, 256, 0, stream>>>(M, FW1, Fb1, bscale, loc, G);
    }
    ic_kernel<<<(G + 255) / 256, 256, 0, stream>>>(loc, FW2, Fb2, ic, scalar, G);

    dim3 mg((G + 63) / 64, 2);

    // Macro layer 1 (agg + BN + relu fused)
    gemm_g128<<<mg, 256, 0, stream>>>(loc, MW1, mdinv, mzw, G);
    csr_agg_bn128<<<(G * 32 + 255) / 256, 256, 0, stream>>>(mrowptr, mcol, mzw, mb1, mdinv,
                                                            g1, be1, m1, v1, z1, G);
    // Macro layer 2 -> glob (in d_out)
    gemm_g128<<<mg, 256, 0, stream>>>(z1, MW2, mdinv, mzw, G);
    csr_agg_bn128<<<(G * 32 + 255) / 256, 256, 0, stream>>>(mrowptr, mcol, mzw, mb2, mdinv,
                                                            g2, be2, m2, v2, glob, G);

    // hc = GCN(glob, MW3, mb3)
    gemm_g10<<<(G + 255) / 256, 256, 0, stream>>>(glob, MW3, mb3, mdrecip, zw3, hc, G);
    edge_agg10<<<(EM + 255) / 256, 256, 0, stream>>>(ms, md, mdinv, zw3, hc, EM);
}

// Round 11
// 753.492 us; speedup vs baseline: 1.2234x; 1.0625x over previous
//
#include <hip/hip_runtime.h>
#include <hip/hip_fp16.h>

// ---------------------------------------------------------------------------
// SEAL GNN pipeline.
// R11: segmean_agg vectorized — 16 lanes/node x 4 node-parallel sub-groups
// within one wave (h4 8-byte loads; 512 B/gather-instr vs 128 B scalar form;
// 4x in-flight node chains). Cross-sub reduce via __shfl_xor(16/32).
// (R9's failed split was 4 separate WAVES w/ scalar loads; this is intra-wave.)
// Everything else: R10 (fp16 A/A2, fused agg chain, XCD scatter, CSR build).
// ---------------------------------------------------------------------------

typedef float nf4 __attribute__((ext_vector_type(4)));
struct __align__(8) h4 { __half2 a, b; };

__global__ void hist_kernel(const int* __restrict__ dst, int* __restrict__ hist, int E) {
    int e = blockIdx.x * blockDim.x + threadIdx.x;
    if (e < E) atomicAdd(&hist[dst[e]], 1);
}

__global__ void finalize_deg(const int* __restrict__ hist, float* __restrict__ dinv,
                             float* __restrict__ drecip, int n) {
    int i = blockIdx.x * blockDim.x + threadIdx.x;
    if (i < n) {
        float c = (float)hist[i] + 1.0f;   // self-loop included
        dinv[i]   = rsqrtf(c);
        drecip[i] = 1.0f / c;
    }
}

// Exclusive scan, stage 1: 1024 counts per 256-thread block.
__global__ __launch_bounds__(256) void scan1(const int* __restrict__ cnt, int* __restrict__ pre,
                                             int* __restrict__ bsum, int n) {
    __shared__ int s[256];
    int base = blockIdx.x * 1024;
    int t = threadIdx.x;
    int v[4];
    int loc = 0;
#pragma unroll
    for (int j = 0; j < 4; j++) {
        int i = base + t * 4 + j;
        v[j] = (i < n) ? cnt[i] : 0;
        loc += v[j];
    }
    s[t] = loc;
    __syncthreads();
    for (int off = 1; off < 256; off <<= 1) {
        int x = (t >= off) ? s[t - off] : 0;
        __syncthreads();
        s[t] += x;
        __syncthreads();
    }
    int run = s[t] - loc;
    if (t == 255) bsum[blockIdx.x] = s[255];
#pragma unroll
    for (int j = 0; j < 4; j++) {
        int i = base + t * 4 + j;
        if (i < n) pre[i] = run;
        run += v[j];
    }
}

// Stage 2: exclusive scan of block sums in place (nb <= 512).
__global__ __launch_bounds__(512) void scan2(int* __restrict__ bsum, int nb) {
    __shared__ int s[512];
    int t = threadIdx.x;
    int v = (t < nb) ? bsum[t] : 0;
    s[t] = v;
    __syncthreads();
    for (int off = 1; off < 512; off <<= 1) {
        int x = (t >= off) ? s[t - off] : 0;
        __syncthreads();
        s[t] += x;
        __syncthreads();
    }
    if (t < nb) bsum[t] = s[t] - v;
}

// Stage 3: add block offsets; also initializes cursor; writes rowptr[n] = E.
__global__ void scan3(int* __restrict__ pre, const int* __restrict__ bsum,
                      int* __restrict__ cursor, int n, int E) {
    int i = blockIdx.x * blockDim.x + threadIdx.x;
    if (i < n) {
        int v = pre[i] + bsum[i >> 10];
        pre[i] = v;
        cursor[i] = v;
    }
    if (i == 0) pre[n] = E;
}

// XCD-bucketed scatter (see R6 comment).
__global__ __launch_bounds__(256) void scatter_xcd(const int* __restrict__ src,
                                                   const int* __restrict__ dst,
                                                   int* __restrict__ cursor,
                                                   int* __restrict__ col,
                                                   int E, int per_chunk, int npx) {
    int bucket = blockIdx.x & 7;
    int chunk  = blockIdx.x >> 3;
    int lo = bucket * npx;
    int hi = lo + npx;
    int e0 = chunk * per_chunk;
    int e1 = min(e0 + per_chunk, E);
    for (int e = e0 + threadIdx.x; e < e1; e += 256) {
        int d = dst[e];
        if (d < lo || d >= hi) continue;
        int p = atomicAdd(&cursor[d], 1);
        col[p] = src[e];
    }
}

// Simple scatter for the tiny macro graph.
__global__ void scatter_kernel(const int* __restrict__ src, const int* __restrict__ dst,
                               int* __restrict__ cursor, int* __restrict__ col, int E) {
    int e = blockIdx.x * blockDim.x + threadIdx.x;
    if (e >= E) return;
    int p = atomicAdd(&cursor[dst[e]], 1);
    col[p] = src[e];
}

// Macro aggregation with fused BatchNorm(eval)+ReLU (fp32, tiny).
__global__ __launch_bounds__(256) void csr_agg_bn128(const int* __restrict__ rowptr,
                                                     const int* __restrict__ col,
                                                     const float* __restrict__ A,
                                                     const float* __restrict__ bias,
                                                     const float* __restrict__ dinv,
                                                     const float* __restrict__ gam,
                                                     const float* __restrict__ bet,
                                                     const float* __restrict__ mean,
                                                     const float* __restrict__ var,
                                                     float* __restrict__ Z, int N) {
    constexpr int F = 128, TPN = 32, NPB = 8;
    int node = blockIdx.x * NPB + threadIdx.x / TPN;
    int lane = threadIdx.x % TPN;
    if (node >= N) return;
    int c = lane * 4;
    float4 acc = *(const float4*)&A[(size_t)node * F + c];
    int e0 = rowptr[node], e1 = rowptr[node + 1];
    int e = e0;
    for (; e + 4 <= e1; e += 4) {
        int s0 = col[e + 0], s1 = col[e + 1], s2 = col[e + 2], s3 = col[e + 3];
        float4 v0 = *(const float4*)&A[(size_t)s0 * F + c];
        float4 v1 = *(const float4*)&A[(size_t)s1 * F + c];
        float4 v2 = *(const float4*)&A[(size_t)s2 * F + c];
        float4 v3 = *(const float4*)&A[(size_t)s3 * F + c];
        acc.x += v0.x + v1.x + v2.x + v3.x;
        acc.y += v0.y + v1.y + v2.y + v3.y;
        acc.z += v0.z + v1.z + v2.z + v3.z;
        acc.w += v0.w + v1.w + v2.w + v3.w;
    }
    for (; e < e1; e++) {
        int s = col[e];
        float4 v = *(const float4*)&A[(size_t)s * F + c];
        acc.x += v.x; acc.y += v.y; acc.z += v.z; acc.w += v.w;
    }
    float dv = dinv[node];
    float4 b4 = *(const float4*)&bias[c];
    float4 g4 = *(const float4*)&gam[c];
    float4 be4 = *(const float4*)&bet[c];
    float4 m4 = *(const float4*)&mean[c];
    float4 v4 = *(const float4*)&var[c];
    float4 o;
    o.x = fmaxf((acc.x * dv + b4.x - m4.x) * rsqrtf(v4.x + 1e-5f) * g4.x + be4.x, 0.f);
    o.y = fmaxf((acc.y * dv + b4.y - m4.y) * rsqrtf(v4.y + 1e-5f) * g4.y + be4.y, 0.f);
    o.z = fmaxf((acc.z * dv + b4.z - m4.z) * rsqrtf(v4.z + 1e-5f) * g4.z + be4.z, 0.f);
    o.w = fmaxf((acc.w * dv + b4.w - m4.w) * rsqrtf(v4.w + 1e-5f) * g4.w + be4.w, 0.f);
    *(float4*)&Z[(size_t)node * F + c] = o;
}

// Layer-1 GEMM: A_h = fp16( (X @ W1) * dinv[row] ). W from global (L1-resident).
__global__ __launch_bounds__(256) void gemm_n64(const float* __restrict__ X,
                                                const float* __restrict__ W,
                                                const float* __restrict__ dinv,
                                                __half* __restrict__ XW, int N) {
    __shared__ float Xs[64][68];
    const int tid = threadIdx.x;
    const int tc = tid & 15;
    const int tr = tid >> 4;
    const int r0 = blockIdx.x * 64;

#pragma unroll
    for (int p = 0; p < 4; p++) {
        int row = p * 16 + (tid >> 4);
        int col = (tid & 15) * 4;
        float4 v = make_float4(0.f, 0.f, 0.f, 0.f);
        if (r0 + row < N) {
            nf4 nv = __builtin_nontemporal_load((const nf4*)&X[(size_t)(r0 + row) * 64 + col]);
            v = make_float4(nv.x, nv.y, nv.z, nv.w);
        }
        *(float4*)&Xs[row][col] = v;
    }
    __syncthreads();

    float acc[4][4];
#pragma unroll
    for (int i = 0; i < 4; i++)
#pragma unroll
        for (int j = 0; j < 4; j++) acc[i][j] = 0.f;

    const float* wp = W + tc * 4;
#pragma unroll 8
    for (int k = 0; k < 64; k++) {
        float4 wv = *(const float4*)&wp[k * 64];
        float x0 = Xs[tr * 4 + 0][k];
        float x1 = Xs[tr * 4 + 1][k];
        float x2 = Xs[tr * 4 + 2][k];
        float x3 = Xs[tr * 4 + 3][k];
        acc[0][0] += x0 * wv.x; acc[0][1] += x0 * wv.y; acc[0][2] += x0 * wv.z; acc[0][3] += x0 * wv.w;
        acc[1][0] += x1 * wv.x; acc[1][1] += x1 * wv.y; acc[1][2] += x1 * wv.z; acc[1][3] += x1 * wv.w;
        acc[2][0] += x2 * wv.x; acc[2][1] += x2 * wv.y; acc[2][2] += x2 * wv.z; acc[2][3] += x2 * wv.w;
        acc[3][0] += x3 * wv.x; acc[3][1] += x3 * wv.y; acc[3][2] += x3 * wv.z; acc[3][3] += x3 * wv.w;
    }

#pragma unroll
    for (int i = 0; i < 4; i++) {
        int row = r0 + tr * 4 + i;
        if (row >= N) continue;
        float dv = dinv[row];
        h4 o;
        o.a = __floats2half2_rn(acc[i][0] * dv, acc[i][1] * dv);
        o.b = __floats2half2_rn(acc[i][2] * dv, acc[i][3] * dv);
        *(h4*)&XW[(size_t)row * 64 + tc * 4] = o;
    }
}

// Layer-2 fused: X-tile = relu(dinv*(A[row]+sum A[col]) + b_prev) into LDS
// (gathering fp16 rows, fp32 accumulate), then A2_h = fp16((Xs@W2)*dinv[row]).
__global__ __launch_bounds__(256) void gemm_agg_n64(const int* __restrict__ rowptr,
                                                    const int* __restrict__ col,
                                                    const __half* __restrict__ A,
                                                    const float* __restrict__ b_prev,
                                                    const float* __restrict__ W,
                                                    const float* __restrict__ dinv,
                                                    __half* __restrict__ XW, int N) {
    __shared__ float Xs[64][68];
    const int tid = threadIdx.x;
    const int tc = tid & 15;
    const int tr = tid >> 4;
    const int r0 = blockIdx.x * 64;

#pragma unroll
    for (int p = 0; p < 4; p++) {
        int row = p * 16 + (tid >> 4);
        int node = r0 + row;
        int c = (tid & 15) * 4;
        float4 acc = make_float4(0.f, 0.f, 0.f, 0.f);
        if (node < N) {
            h4 sv = *(const h4*)&A[(size_t)node * 64 + c];
            float2 f0 = __half22float2(sv.a);
            float2 f1 = __half22float2(sv.b);
            acc = make_float4(f0.x, f0.y, f1.x, f1.y);
            int e0 = rowptr[node], e1 = rowptr[node + 1];
            int e = e0;
            for (; e + 4 <= e1; e += 4) {
                int s0 = col[e + 0], s1 = col[e + 1], s2 = col[e + 2], s3 = col[e + 3];
                h4 v0 = *(const h4*)&A[(size_t)s0 * 64 + c];
                h4 v1 = *(const h4*)&A[(size_t)s1 * 64 + c];
                h4 v2 = *(const h4*)&A[(size_t)s2 * 64 + c];
                h4 v3 = *(const h4*)&A[(size_t)s3 * 64 + c];
                float2 a0 = __half22float2(v0.a), b0 = __half22float2(v0.b);
                float2 a1 = __half22float2(v1.a), b1 = __half22float2(v1.b);
                float2 a2 = __half22float2(v2.a), b2 = __half22float2(v2.b);
                float2 a3 = __half22float2(v3.a), b3 = __half22float2(v3.b);
                acc.x += a0.x + a1.x + a2.x + a3.x;
                acc.y += a0.y + a1.y + a2.y + a3.y;
                acc.z += b0.x + b1.x + b2.x + b3.x;
                acc.w += b0.y + b1.y + b2.y + b3.y;
            }
            for (; e < e1; e++) {
                int s = col[e];
                h4 v = *(const h4*)&A[(size_t)s * 64 + c];
                float2 a = __half22float2(v.a), b = __half22float2(v.b);
                acc.x += a.x; acc.y += a.y; acc.z += b.x; acc.w += b.y;
            }
            float dv = dinv[node];
            float4 b4 = *(const float4*)&b_prev[c];
            acc.x = fmaxf(acc.x * dv + b4.x, 0.f);
            acc.y = fmaxf(acc.y * dv + b4.y, 0.f);
            acc.z = fmaxf(acc.z * dv + b4.z, 0.f);
            acc.w = fmaxf(acc.w * dv + b4.w, 0.f);
        }
        *(float4*)&Xs[row][c] = acc;
    }
    __syncthreads();

    float acc[4][4];
#pragma unroll
    for (int i = 0; i < 4; i++)
#pragma unroll
        for (int j = 0; j < 4; j++) acc[i][j] = 0.f;

    const float* wp = W + tc * 4;
#pragma unroll 8
    for (int k = 0; k < 64; k++) {
        float4 wv = *(const float4*)&wp[k * 64];
        float x0 = Xs[tr * 4 + 0][k];
        float x1 = Xs[tr * 4 + 1][k];
        float x2 = Xs[tr * 4 + 2][k];
        float x3 = Xs[tr * 4 + 3][k];
        acc[0][0] += x0 * wv.x; acc[0][1] += x0 * wv.y; acc[0][2] += x0 * wv.z; acc[0][3] += x0 * wv.w;
        acc[1][0] += x1 * wv.x; acc[1][1] += x1 * wv.y; acc[1][2] += x1 * wv.z; acc[1][3] += x1 * wv.w;
        acc[2][0] += x2 * wv.x; acc[2][1] += x2 * wv.y; acc[2][2] += x2 * wv.z; acc[2][3] += x2 * wv.w;
        acc[3][0] += x3 * wv.x; acc[3][1] += x3 * wv.y; acc[3][2] += x3 * wv.z; acc[3][3] += x3 * wv.w;
    }

#pragma unroll
    for (int i = 0; i < 4; i++) {
        int row = r0 + tr * 4 + i;
        if (row >= N) continue;
        float dv = dinv[row];
        h4 o;
        o.a = __floats2half2_rn(acc[i][0] * dv, acc[i][1] * dv);
        o.b = __floats2half2_rn(acc[i][2] * dv, acc[i][3] * dv);
        *(h4*)&XW[(size_t)row * 64 + tc * 4] = o;
    }
}

// Pooling fused with layer-2 aggregation. One wave per graph:
// 16 lanes/node (h4 loads over 64 cols) x 4 node-parallel sub-groups.
__global__ __launch_bounds__(64) void segmean_agg(const int* __restrict__ rowptr,
                                                  const int* __restrict__ col,
                                                  const __half* __restrict__ A2,
                                                  const float* __restrict__ b2,
                                                  const float* __restrict__ dinv,
                                                  const int* __restrict__ batch,
                                                  float* __restrict__ M,
                                                  float* __restrict__ bscale, int N) {
    int g = blockIdx.x;
    int lane = threadIdx.x & 15;   // column group: cols lane*4 .. lane*4+3
    int sub  = threadIdx.x >> 4;   // node-parallel sub-group 0..3
    int c = lane * 4;

    int lo = 0, hi = N;
    while (lo < hi) { int m = (lo + hi) >> 1; if (batch[m] < g) lo = m + 1; else hi = m; }
    int start = lo;
    hi = N;
    while (lo < hi) { int m = (lo + hi) >> 1; if (batch[m] < g + 1) lo = m + 1; else hi = m; }
    int end = lo;

    float4 b4 = *(const float4*)&b2[c];
    float4 msum = make_float4(0.f, 0.f, 0.f, 0.f);

    for (int node = start + sub; node < end; node += 4) {
        h4 sv = *(const h4*)&A2[(size_t)node * 64 + c];
        float2 f0 = __half22float2(sv.a);
        float2 f1 = __half22float2(sv.b);
        float4 acc = make_float4(f0.x, f0.y, f1.x, f1.y);
        int e0 = rowptr[node], e1 = rowptr[node + 1];
        int e = e0;
        for (; e + 4 <= e1; e += 4) {
            int s0 = col[e + 0], s1 = col[e + 1], s2 = col[e + 2], s3 = col[e + 3];
            h4 v0 = *(const h4*)&A2[(size_t)s0 * 64 + c];
            h4 v1 = *(const h4*)&A2[(size_t)s1 * 64 + c];
            h4 v2 = *(const h4*)&A2[(size_t)s2 * 64 + c];
            h4 v3 = *(const h4*)&A2[(size_t)s3 * 64 + c];
            float2 a0 = __half22float2(v0.a), q0 = __half22float2(v0.b);
            float2 a1 = __half22float2(v1.a), q1 = __half22float2(v1.b);
            float2 a2 = __half22float2(v2.a), q2 = __half22float2(v2.b);
            float2 a3 = __half22float2(v3.a), q3 = __half22float2(v3.b);
            acc.x += a0.x + a1.x + a2.x + a3.x;
            acc.y += a0.y + a1.y + a2.y + a3.y;
            acc.z += q0.x + q1.x + q2.x + q3.x;
            acc.w += q0.y + q1.y + q2.y + q3.y;
        }
        for (; e < e1; e++) {
            int s = col[e];
            h4 v = *(const h4*)&A2[(size_t)s * 64 + c];
            float2 a = __half22float2(v.a), q = __half22float2(v.b);
            acc.x += a.x; acc.y += a.y; acc.z += q.x; acc.w += q.y;
        }
        float dv = dinv[node];
        msum.x += fmaxf(acc.x * dv + b4.x, 0.f);
        msum.y += fmaxf(acc.y * dv + b4.y, 0.f);
        msum.z += fmaxf(acc.z * dv + b4.z, 0.f);
        msum.w += fmaxf(acc.w * dv + b4.w, 0.f);
    }

    // reduce across the 4 sub-groups (lanes differ by 16 and 32 in the wave)
    msum.x += __shfl_xor(msum.x, 16); msum.y += __shfl_xor(msum.y, 16);
    msum.z += __shfl_xor(msum.z, 16); msum.w += __shfl_xor(msum.w, 16);
    msum.x += __shfl_xor(msum.x, 32); msum.y += __shfl_xor(msum.y, 32);
    msum.z += __shfl_xor(msum.z, 32); msum.w += __shfl_xor(msum.w, 32);

    int cnt = end - start;
    float inv = (cnt > 0) ? 1.f / (float)cnt : 0.f;
    if (sub == 0) {
        float4 o;
        o.x = msum.x * inv; o.y = msum.y * inv;
        o.z = msum.z * inv; o.w = msum.w * inv;
        *(float4*)&M[(size_t)g * 64 + c] = o;
        if (lane == 0) bscale[g] = (cnt > 0) ? 1.f : 0.f;
    }
}

// loc = M @ FW1 + bscale*Fb1   [G x 64 @ 64 x 128]; grid.y = 2 col-tiles.
__global__ __launch_bounds__(256) void loc_gemm(const float* __restrict__ M,
                                                const float* __restrict__ FW1,
                                                const float* __restrict__ Fb1,
                                                const float* __restrict__ bscale,
                                                float* __restrict__ loc, int G) {
    __shared__ float Xs[64][68];
    __shared__ float Ws[64][64];
    __shared__ float bs[64];
    const int tid = threadIdx.x;
    const int tc = tid & 15;
    const int tr = tid >> 4;
    const int r0 = blockIdx.x * 64;
    const int c0 = blockIdx.y * 64;

    for (int i = tid; i < 4096; i += 256)
        Ws[i >> 6][i & 63] = FW1[(size_t)(i >> 6) * 128 + c0 + (i & 63)];
    if (tid < 64) bs[tid] = Fb1[c0 + tid];
#pragma unroll
    for (int p = 0; p < 4; p++) {
        int row = p * 16 + (tid >> 4);
        int col = (tid & 15) * 4;
        float4 v = make_float4(0.f, 0.f, 0.f, 0.f);
        if (r0 + row < G) v = *(const float4*)&M[(size_t)(r0 + row) * 64 + col];
        *(float4*)&Xs[row][col] = v;
    }
    __syncthreads();

    float acc[4][4];
#pragma unroll
    for (int i = 0; i < 4; i++)
#pragma unroll
        for (int j = 0; j < 4; j++) acc[i][j] = 0.f;

#pragma unroll 8
    for (int k = 0; k < 64; k++) {
        float4 wv = *(const float4*)&Ws[k][tc * 4];
        float x0 = Xs[tr * 4 + 0][k];
        float x1 = Xs[tr * 4 + 1][k];
        float x2 = Xs[tr * 4 + 2][k];
        float x3 = Xs[tr * 4 + 3][k];
        acc[0][0] += x0 * wv.x; acc[0][1] += x0 * wv.y; acc[0][2] += x0 * wv.z; acc[0][3] += x0 * wv.w;
        acc[1][0] += x1 * wv.x; acc[1][1] += x1 * wv.y; acc[1][2] += x1 * wv.z; acc[1][3] += x1 * wv.w;
        acc[2][0] += x2 * wv.x; acc[2][1] += x2 * wv.y; acc[2][2] += x2 * wv.z; acc[2][3] += x2 * wv.w;
        acc[3][0] += x3 * wv.x; acc[3][1] += x3 * wv.y; acc[3][2] += x3 * wv.z; acc[3][3] += x3 * wv.w;
    }

#pragma unroll
    for (int i = 0; i < 4; i++) {
        int row = r0 + tr * 4 + i;
        if (row >= G) continue;
        float sc = bscale[row];
        float4 o;
        o.x = acc[i][0] + sc * bs[tc * 4 + 0];
        o.y = acc[i][1] + sc * bs[tc * 4 + 1];
        o.z = acc[i][2] + sc * bs[tc * 4 + 2];
        o.w = acc[i][3] + sc * bs[tc * 4 + 3];
        *(float4*)&loc[(size_t)row * 128 + c0 + tc * 4] = o;
    }
}

// ic = loc @ FW2 + Fb2; thread 0 also writes the trailing scalar 0.
__global__ __launch_bounds__(256) void ic_kernel(const float* __restrict__ loc,
                                                 const float* __restrict__ FW2,
                                                 const float* __restrict__ Fb2,
                                                 float* __restrict__ ic,
                                                 float* __restrict__ scalar_out, int G) {
    __shared__ float Ws[1280];
    __shared__ float bs[10];
    for (int i = threadIdx.x; i < 1280; i += 256) Ws[i] = FW2[i];
    if (threadIdx.x < 10) bs[threadIdx.x] = Fb2[threadIdx.x];
    __syncthreads();
    int g = blockIdx.x * 256 + threadIdx.x;
    if (g == 0) scalar_out[0] = 0.f;
    if (g >= G) return;
    float acc[10];
#pragma unroll
    for (int j = 0; j < 10; j++) acc[j] = bs[j];
    const float* xr = loc + (size_t)g * 128;
    for (int k = 0; k < 128; k++) {
        float xv = xr[k];
#pragma unroll
        for (int j = 0; j < 10; j++) acc[j] += xv * Ws[k * 10 + j];
    }
    float* o = ic + (size_t)g * 10;
#pragma unroll
    for (int j = 0; j < 10; j++) o[j] = acc[j];
}

// ZW = (X @ W) * dinv[row]  [G x 128 @ 128 x 128]; 64x64 tile (grid.y = 2 col tiles).
__global__ __launch_bounds__(256) void gemm_g128(const float* __restrict__ X,
                                                 const float* __restrict__ W,
                                                 const float* __restrict__ dinv,
                                                 float* __restrict__ ZW, int G) {
    __shared__ float Xs[64][68];
    __shared__ float Ws[64][64];
    const int tid = threadIdx.x;
    const int tc = tid & 15;
    const int tr = tid >> 4;
    const int r0 = blockIdx.x * 64;
    const int c0 = blockIdx.y * 64;

    float acc[4][4];
#pragma unroll
    for (int i = 0; i < 4; i++)
#pragma unroll
        for (int j = 0; j < 4; j++) acc[i][j] = 0.f;

    for (int kc = 0; kc < 2; kc++) {
        __syncthreads();
        for (int i = tid; i < 4096; i += 256)
            Ws[i >> 6][i & 63] = W[(size_t)(kc * 64 + (i >> 6)) * 128 + c0 + (i & 63)];
#pragma unroll
        for (int p = 0; p < 4; p++) {
            int row = p * 16 + (tid >> 4);
            int col = (tid & 15) * 4;
            float4 v = make_float4(0.f, 0.f, 0.f, 0.f);
            if (r0 + row < G) v = *(const float4*)&X[(size_t)(r0 + row) * 128 + kc * 64 + col];
            *(float4*)&Xs[row][col] = v;
        }
        __syncthreads();
#pragma unroll 8
        for (int k = 0; k < 64; k++) {
            float4 wv = *(const float4*)&Ws[k][tc * 4];
            float x0 = Xs[tr * 4 + 0][k];
            float x1 = Xs[tr * 4 + 1][k];
            float x2 = Xs[tr * 4 + 2][k];
            float x3 = Xs[tr * 4 + 3][k];
            acc[0][0] += x0 * wv.x; acc[0][1] += x0 * wv.y; acc[0][2] += x0 * wv.z; acc[0][3] += x0 * wv.w;
            acc[1][0] += x1 * wv.x; acc[1][1] += x1 * wv.y; acc[1][2] += x1 * wv.z; acc[1][3] += x1 * wv.w;
            acc[2][0] += x2 * wv.x; acc[2][1] += x2 * wv.y; acc[2][2] += x2 * wv.z; acc[2][3] += x2 * wv.w;
            acc[3][0] += x3 * wv.x; acc[3][1] += x3 * wv.y; acc[3][2] += x3 * wv.z; acc[3][3] += x3 * wv.w;
        }
    }

#pragma unroll
    for (int i = 0; i < 4; i++) {
        int row = r0 + tr * 4 + i;
        if (row >= G) continue;
        float dv = dinv[row];
        *(float4*)&ZW[(size_t)row * 128 + c0 + tc * 4] =
            make_float4(acc[i][0] * dv, acc[i][1] * dv, acc[i][2] * dv, acc[i][3] * dv);
    }
}

// ZW = X @ W [G x 128 @ 128 x 10]; HC = ZW*mdrecip + bias
__global__ __launch_bounds__(256) void gemm_g10(const float* __restrict__ X,
                                                const float* __restrict__ W,
                                                const float* __restrict__ bias,
                                                const float* __restrict__ mdrecip,
                                                float* __restrict__ ZW,
                                                float* __restrict__ HC, int G) {
    __shared__ float Ws[1280];
    __shared__ float bs[10];
    for (int i = threadIdx.x; i < 1280; i += 256) Ws[i] = W[i];
    if (threadIdx.x < 10) bs[threadIdx.x] = bias[threadIdx.x];
    __syncthreads();
    int g = blockIdx.x * 256 + threadIdx.x;
    if (g >= G) return;
    float acc[10];
#pragma unroll
    for (int j = 0; j < 10; j++) acc[j] = 0.f;
    const float4* xr = (const float4*)(X + (size_t)g * 128);
#pragma unroll 4
    for (int k4 = 0; k4 < 32; k4++) {
        float4 v = xr[k4];
        float xv[4] = {v.x, v.y, v.z, v.w};
#pragma unroll
        for (int d = 0; d < 4; d++) {
            float xs = xv[d];
            int k = k4 * 4 + d;
#pragma unroll
            for (int j = 0; j < 10; j++) acc[j] += xs * Ws[k * 10 + j];
        }
    }
    float dr = mdrecip[g];
    float* zw = ZW + (size_t)g * 10;
    float* hc = HC + (size_t)g * 10;
#pragma unroll
    for (int j = 0; j < 10; j++) {
        zw[j] = acc[j];
        hc[j] = acc[j] * dr + bs[j];
    }
}

// HC[md] += ZW[ms] * mdinv[ms]*mdinv[md]  (10 features, tiny)
__global__ void edge_agg10(const int* __restrict__ ms, const int* __restrict__ md,
                           const float* __restrict__ mdinv, const float* __restrict__ ZW,
                           float* __restrict__ HC, int EM) {
    int e = blockIdx.x * blockDim.x + threadIdx.x;
    if (e >= EM) return;
    int s = ms[e], d = md[e];
    float w = mdinv[s] * mdinv[d];
    const float* zr = ZW + (size_t)s * 10;
    float* out = HC + (size_t)d * 10;
#pragma unroll
    for (int j = 0; j < 10; j++) atomicAdd(out + j, zr[j] * w);
}

extern "C" void kernel_launch(void* const* d_in, const int* in_sizes, int n_in,
                              void* d_out, int out_size, void* d_ws, size_t ws_size,
                              hipStream_t stream) {
    const float* x    = (const float*)d_in[0];
    const int*   ei   = (const int*)d_in[1];
    const int*   batch= (const int*)d_in[2];
    const int*   me   = (const int*)d_in[3];
    const float* W1   = (const float*)d_in[5];
    const float* b1   = (const float*)d_in[6];
    const float* W2   = (const float*)d_in[7];
    const float* b2   = (const float*)d_in[8];
    const float* FW1  = (const float*)d_in[9];
    const float* Fb1  = (const float*)d_in[10];
    const float* FW2  = (const float*)d_in[11];
    const float* Fb2  = (const float*)d_in[12];
    const float* MW1  = (const float*)d_in[13];
    const float* mb1  = (const float*)d_in[14];
    const float* g1   = (const float*)d_in[15];
    const float* be1  = (const float*)d_in[16];
    const float* m1   = (const float*)d_in[17];
    const float* v1   = (const float*)d_in[18];
    const float* MW2  = (const float*)d_in[19];
    const float* mb2  = (const float*)d_in[20];
    const float* g2   = (const float*)d_in[21];
    const float* be2  = (const float*)d_in[22];
    const float* m2   = (const float*)d_in[23];
    const float* v2   = (const float*)d_in[24];
    const float* MW3  = (const float*)d_in[25];
    const float* mb3  = (const float*)d_in[26];

    const int N  = in_sizes[0] / 64;
    const int E  = in_sizes[1] / 2;
    const int EM = in_sizes[3] / 2;
    const int G  = (out_size - 1) / 276;

    float* out    = (float*)d_out;
    float* hc     = out;
    float* ic     = out + (size_t)G * 10;
    float* loc    = out + (size_t)G * 20;
    float* glob   = out + (size_t)G * 20 + (size_t)G * 128;
    float* scalar = out + (size_t)G * 276;

    char*  ws  = (char*)d_ws;
    size_t off = 0;
    auto alloc = [&](size_t bytes) -> void* {
        void* p = (void*)(ws + off);
        off += (bytes + 255) & ~(size_t)255;
        return p;
    };
    int*    hist    = (int*)alloc((size_t)(N + 1) * 4);
    int*    rowptr  = (int*)alloc((size_t)(N + 1) * 4);
    int*    cursor  = (int*)alloc((size_t)N * 4);
    int*    bsum    = (int*)alloc(512 * 4);
    int*    col     = (int*)alloc((size_t)E * 4);
    float*  dinv    = (float*)alloc((size_t)N * 4);
    float*  drecip  = (float*)alloc((size_t)N * 4);
    int*    mhist   = (int*)alloc((size_t)(G + 1) * 4);
    int*    mrowptr = (int*)alloc((size_t)(G + 1) * 4);
    int*    mcursor = (int*)alloc((size_t)G * 4);
    int*    mbsum   = (int*)alloc(512 * 4);
    int*    mcol    = (int*)alloc((size_t)EM * 4);
    float*  mdinv   = (float*)alloc((size_t)G * 4);
    float*  mdrecip = (float*)alloc((size_t)G * 4);
    __half* A       = (__half*)alloc((size_t)N * 64 * 2);   // fp16 xw1*dinv
    __half* A2      = (__half*)alloc((size_t)N * 64 * 2);   // fp16 xw2*dinv
    float*  M       = (float*)alloc((size_t)G * 64 * 4);    // segment means
    float*  bscale  = (float*)alloc((size_t)G * 4);
    float*  mzw     = (float*)alloc((size_t)G * 128 * 4);
    float*  z1      = (float*)alloc((size_t)G * 128 * 4);
    float*  zw3     = (float*)alloc((size_t)G * 10 * 4);
    (void)ws_size;

    const int* src = ei;
    const int* dst = ei + E;
    const int* ms  = me;
    const int* md  = me + EM;

    // ---- degrees + CSR build (node graph and macro graph) ----
    hipMemsetAsync(hist, 0, (size_t)(N + 1) * 4, stream);
    hipMemsetAsync(mhist, 0, (size_t)(G + 1) * 4, stream);
    hist_kernel<<<(E + 255) / 256, 256, 0, stream>>>(dst, hist, E);
    hist_kernel<<<(EM + 255) / 256, 256, 0, stream>>>(md, mhist, EM);
    finalize_deg<<<(N + 255) / 256, 256, 0, stream>>>(hist, dinv, drecip, N);
    finalize_deg<<<(G + 255) / 256, 256, 0, stream>>>(mhist, mdinv, mdrecip, G);

    const int nb1 = (N + 1023) / 1024;
    scan1<<<nb1, 256, 0, stream>>>(hist, rowptr, bsum, N);
    scan2<<<1, 512, 0, stream>>>(bsum, nb1);
    scan3<<<(N + 255) / 256, 256, 0, stream>>>(rowptr, bsum, cursor, N, E);
    const int nb2 = (G + 1023) / 1024;
    scan1<<<nb2, 256, 0, stream>>>(mhist, mrowptr, mbsum, G);
    scan2<<<1, 512, 0, stream>>>(mbsum, nb2);
    scan3<<<(G + 255) / 256, 256, 0, stream>>>(mrowptr, mbsum, mcursor, G, EM);

    {
        const int nchunks = 2048;
        const int per_chunk = (E + nchunks - 1) / nchunks;
        const int npx = (N + 7) / 8;
        scatter_xcd<<<nchunks * 8, 256, 0, stream>>>(src, dst, cursor, col, E, per_chunk, npx);
    }
    scatter_kernel<<<(EM + 255) / 256, 256, 0, stream>>>(ms, md, mcursor, mcol, EM);

    const int nblk = (N + 63) / 64;

    // Layer 1 GEMM -> fp16 A
    gemm_n64<<<nblk, 256, 0, stream>>>(x, W1, dinv, A, N);
    // Layer 2 GEMM with fused layer-1 aggregation -> fp16 A2
    gemm_agg_n64<<<nblk, 256, 0, stream>>>(rowptr, col, A, b1, W2, dinv, A2, N);
    // Pooling with fused layer-2 aggregation (vectorized, 4-node intra-wave)
    segmean_agg<<<G, 64, 0, stream>>>(rowptr, col, A2, b2, dinv, batch, M, bscale, N);
    {
        dim3 lg((G + 63) / 64, 2);
        loc_gemm<<<lg, 256, 0, stream>>>(M, FW1, Fb1, bscale, loc, G);
    }
    ic_kernel<<<(G + 255) / 256, 256, 0, stream>>>(loc, FW2, Fb2, ic, scalar, G);

    dim3 mg((G + 63) / 64, 2);

    // Macro layer 1 (agg + BN + relu fused)
    gemm_g128<<<mg, 256, 0, stream>>>(loc, MW1, mdinv, mzw, G);
    csr_agg_bn128<<<(G * 32 + 255) / 256, 256, 0, stream>>>(mrowptr, mcol, mzw, mb1, mdinv,
                                                            g1, be1, m1, v1, z1, G);
    // Macro layer 2 -> glob (in d_out)
    gemm_g128<<<mg, 256, 0, stream>>>(z1, MW2, mdinv, mzw, G);
    csr_agg_bn128<<<(G * 32 + 255) / 256, 256, 0, stream>>>(mrowptr, mcol, mzw, mb2, mdinv,
                                                            g2, be2, m2, v2, glob, G);

    // hc = GCN(glob, MW3, mb3)
    gemm_g10<<<(G + 255) / 256, 256, 0, stream>>>(glob, MW3, mb3, mdrecip, zw3, hc, G);
    edge_agg10<<<(EM + 255) / 256, 256, 0, stream>>>(ms, md, mdinv, zw3, hc, EM);
}

// Round 12
// 723.765 us; speedup vs baseline: 1.2736x; 1.0411x over previous
//
#include <hip/hip_runtime.h>
#include <hip/hip_fp16.h>

// ---------------------------------------------------------------------------
// SEAL GNN pipeline.
// R12: (1) gemm_agg_n64's GEMM phase moved to MFMA (v_mfma_f32_16x16x16_f16):
// staged tile stored fp16 in LDS (conflict-free 68-half rows), W2 converted to
// fp16 transposed in LDS; 16 MFMA per wave replace 1024 scalar FMA per thread
// (R11 counters: VALUBusy 46% at 82% occ -> GEMM-on-VALU was the binding
// resource). (2) segmean_agg: 2 graphs per 128-thread block (64-thread blocks
// capped at 16 blocks/CU = 50% occ).
// ---------------------------------------------------------------------------

typedef float nf4 __attribute__((ext_vector_type(4)));
typedef _Float16 v4h __attribute__((ext_vector_type(4)));
typedef float v4f __attribute__((ext_vector_type(4)));
struct __align__(8) h4 { __half2 a, b; };

__global__ void hist_kernel(const int* __restrict__ dst, int* __restrict__ hist, int E) {
    int e = blockIdx.x * blockDim.x + threadIdx.x;
    if (e < E) atomicAdd(&hist[dst[e]], 1);
}

__global__ void finalize_deg(const int* __restrict__ hist, float* __restrict__ dinv,
                             float* __restrict__ drecip, int n) {
    int i = blockIdx.x * blockDim.x + threadIdx.x;
    if (i < n) {
        float c = (float)hist[i] + 1.0f;   // self-loop included
        dinv[i]   = rsqrtf(c);
        drecip[i] = 1.0f / c;
    }
}

// Exclusive scan, stage 1: 1024 counts per 256-thread block.
__global__ __launch_bounds__(256) void scan1(const int* __restrict__ cnt, int* __restrict__ pre,
                                             int* __restrict__ bsum, int n) {
    __shared__ int s[256];
    int base = blockIdx.x * 1024;
    int t = threadIdx.x;
    int v[4];
    int loc = 0;
#pragma unroll
    for (int j = 0; j < 4; j++) {
        int i = base + t * 4 + j;
        v[j] = (i < n) ? cnt[i] : 0;
        loc += v[j];
    }
    s[t] = loc;
    __syncthreads();
    for (int off = 1; off < 256; off <<= 1) {
        int x = (t >= off) ? s[t - off] : 0;
        __syncthreads();
        s[t] += x;
        __syncthreads();
    }
    int run = s[t] - loc;
    if (t == 255) bsum[blockIdx.x] = s[255];
#pragma unroll
    for (int j = 0; j < 4; j++) {
        int i = base + t * 4 + j;
        if (i < n) pre[i] = run;
        run += v[j];
    }
}

// Stage 2: exclusive scan of block sums in place (nb <= 512).
__global__ __launch_bounds__(512) void scan2(int* __restrict__ bsum, int nb) {
    __shared__ int s[512];
    int t = threadIdx.x;
    int v = (t < nb) ? bsum[t] : 0;
    s[t] = v;
    __syncthreads();
    for (int off = 1; off < 512; off <<= 1) {
        int x = (t >= off) ? s[t - off] : 0;
        __syncthreads();
        s[t] += x;
        __syncthreads();
    }
    if (t < nb) bsum[t] = s[t] - v;
}

// Stage 3: add block offsets; also initializes cursor; writes rowptr[n] = E.
__global__ void scan3(int* __restrict__ pre, const int* __restrict__ bsum,
                      int* __restrict__ cursor, int n, int E) {
    int i = blockIdx.x * blockDim.x + threadIdx.x;
    if (i < n) {
        int v = pre[i] + bsum[i >> 10];
        pre[i] = v;
        cursor[i] = v;
    }
    if (i == 0) pre[n] = E;
}

// XCD-bucketed scatter (see R6 comment).
__global__ __launch_bounds__(256) void scatter_xcd(const int* __restrict__ src,
                                                   const int* __restrict__ dst,
                                                   int* __restrict__ cursor,
                                                   int* __restrict__ col,
                                                   int E, int per_chunk, int npx) {
    int bucket = blockIdx.x & 7;
    int chunk  = blockIdx.x >> 3;
    int lo = bucket * npx;
    int hi = lo + npx;
    int e0 = chunk * per_chunk;
    int e1 = min(e0 + per_chunk, E);
    for (int e = e0 + threadIdx.x; e < e1; e += 256) {
        int d = dst[e];
        if (d < lo || d >= hi) continue;
        int p = atomicAdd(&cursor[d], 1);
        col[p] = src[e];
    }
}

// Simple scatter for the tiny macro graph.
__global__ void scatter_kernel(const int* __restrict__ src, const int* __restrict__ dst,
                               int* __restrict__ cursor, int* __restrict__ col, int E) {
    int e = blockIdx.x * blockDim.x + threadIdx.x;
    if (e >= E) return;
    int p = atomicAdd(&cursor[dst[e]], 1);
    col[p] = src[e];
}

// Macro aggregation with fused BatchNorm(eval)+ReLU (fp32, tiny).
__global__ __launch_bounds__(256) void csr_agg_bn128(const int* __restrict__ rowptr,
                                                     const int* __restrict__ col,
                                                     const float* __restrict__ A,
                                                     const float* __restrict__ bias,
                                                     const float* __restrict__ dinv,
                                                     const float* __restrict__ gam,
                                                     const float* __restrict__ bet,
                                                     const float* __restrict__ mean,
                                                     const float* __restrict__ var,
                                                     float* __restrict__ Z, int N) {
    constexpr int F = 128, TPN = 32, NPB = 8;
    int node = blockIdx.x * NPB + threadIdx.x / TPN;
    int lane = threadIdx.x % TPN;
    if (node >= N) return;
    int c = lane * 4;
    float4 acc = *(const float4*)&A[(size_t)node * F + c];
    int e0 = rowptr[node], e1 = rowptr[node + 1];
    int e = e0;
    for (; e + 4 <= e1; e += 4) {
        int s0 = col[e + 0], s1 = col[e + 1], s2 = col[e + 2], s3 = col[e + 3];
        float4 v0 = *(const float4*)&A[(size_t)s0 * F + c];
        float4 v1 = *(const float4*)&A[(size_t)s1 * F + c];
        float4 v2 = *(const float4*)&A[(size_t)s2 * F + c];
        float4 v3 = *(const float4*)&A[(size_t)s3 * F + c];
        acc.x += v0.x + v1.x + v2.x + v3.x;
        acc.y += v0.y + v1.y + v2.y + v3.y;
        acc.z += v0.z + v1.z + v2.z + v3.z;
        acc.w += v0.w + v1.w + v2.w + v3.w;
    }
    for (; e < e1; e++) {
        int s = col[e];
        float4 v = *(const float4*)&A[(size_t)s * F + c];
        acc.x += v.x; acc.y += v.y; acc.z += v.z; acc.w += v.w;
    }
    float dv = dinv[node];
    float4 b4 = *(const float4*)&bias[c];
    float4 g4 = *(const float4*)&gam[c];
    float4 be4 = *(const float4*)&bet[c];
    float4 m4 = *(const float4*)&mean[c];
    float4 v4 = *(const float4*)&var[c];
    float4 o;
    o.x = fmaxf((acc.x * dv + b4.x - m4.x) * rsqrtf(v4.x + 1e-5f) * g4.x + be4.x, 0.f);
    o.y = fmaxf((acc.y * dv + b4.y - m4.y) * rsqrtf(v4.y + 1e-5f) * g4.y + be4.y, 0.f);
    o.z = fmaxf((acc.z * dv + b4.z - m4.z) * rsqrtf(v4.z + 1e-5f) * g4.z + be4.z, 0.f);
    o.w = fmaxf((acc.w * dv + b4.w - m4.w) * rsqrtf(v4.w + 1e-5f) * g4.w + be4.w, 0.f);
    *(float4*)&Z[(size_t)node * F + c] = o;
}

// Layer-1 GEMM: A_h = fp16( (X @ W1) * dinv[row] ). W from global (L1-resident).
__global__ __launch_bounds__(256) void gemm_n64(const float* __restrict__ X,
                                                const float* __restrict__ W,
                                                const float* __restrict__ dinv,
                                                __half* __restrict__ XW, int N) {
    __shared__ float Xs[64][68];
    const int tid = threadIdx.x;
    const int tc = tid & 15;
    const int tr = tid >> 4;
    const int r0 = blockIdx.x * 64;

#pragma unroll
    for (int p = 0; p < 4; p++) {
        int row = p * 16 + (tid >> 4);
        int col = (tid & 15) * 4;
        float4 v = make_float4(0.f, 0.f, 0.f, 0.f);
        if (r0 + row < N) {
            nf4 nv = __builtin_nontemporal_load((const nf4*)&X[(size_t)(r0 + row) * 64 + col]);
            v = make_float4(nv.x, nv.y, nv.z, nv.w);
        }
        *(float4*)&Xs[row][col] = v;
    }
    __syncthreads();

    float acc[4][4];
#pragma unroll
    for (int i = 0; i < 4; i++)
#pragma unroll
        for (int j = 0; j < 4; j++) acc[i][j] = 0.f;

    const float* wp = W + tc * 4;
#pragma unroll 8
    for (int k = 0; k < 64; k++) {
        float4 wv = *(const float4*)&wp[k * 64];
        float x0 = Xs[tr * 4 + 0][k];
        float x1 = Xs[tr * 4 + 1][k];
        float x2 = Xs[tr * 4 + 2][k];
        float x3 = Xs[tr * 4 + 3][k];
        acc[0][0] += x0 * wv.x; acc[0][1] += x0 * wv.y; acc[0][2] += x0 * wv.z; acc[0][3] += x0 * wv.w;
        acc[1][0] += x1 * wv.x; acc[1][1] += x1 * wv.y; acc[1][2] += x1 * wv.z; acc[1][3] += x1 * wv.w;
        acc[2][0] += x2 * wv.x; acc[2][1] += x2 * wv.y; acc[2][2] += x2 * wv.z; acc[2][3] += x2 * wv.w;
        acc[3][0] += x3 * wv.x; acc[3][1] += x3 * wv.y; acc[3][2] += x3 * wv.z; acc[3][3] += x3 * wv.w;
    }

#pragma unroll
    for (int i = 0; i < 4; i++) {
        int row = r0 + tr * 4 + i;
        if (row >= N) continue;
        float dv = dinv[row];
        h4 o;
        o.a = __floats2half2_rn(acc[i][0] * dv, acc[i][1] * dv);
        o.b = __floats2half2_rn(acc[i][2] * dv, acc[i][3] * dv);
        *(h4*)&XW[(size_t)row * 64 + tc * 4] = o;
    }
}

// Layer-2 fused: X-tile = relu(dinv*(A[row]+sum A[col]) + b_prev) staged fp16
// into LDS, then A2 = fp16((X @ W2) * dinv[row]) via MFMA 16x16x16 f16.
// Fragment layout (classic, verified): A lane l -> row l&15, k=4*(l>>4)+j;
// B lane l -> col l&15, k=4*(l>>4)+j; C lane l -> col l&15, row=(l>>4)*4+j.
__global__ __launch_bounds__(256) void gemm_agg_n64(const int* __restrict__ rowptr,
                                                    const int* __restrict__ col,
                                                    const __half* __restrict__ A,
                                                    const float* __restrict__ b_prev,
                                                    const float* __restrict__ W,
                                                    const float* __restrict__ dinv,
                                                    __half* __restrict__ XW, int N) {
    __shared__ _Float16 Xh[64][68];    // 136 B rows: 8B-aligned, conflict-free frags
    __shared__ _Float16 WhT[64][68];   // WhT[col][k] = W[k][col], fp16
    const int tid = threadIdx.x;
    const int r0 = blockIdx.x * 64;

    // W2 -> fp16 transposed in LDS
    for (int i = tid; i < 4096; i += 256) {
        int k = i >> 6, c = i & 63;
        WhT[c][k] = (_Float16)W[i];
    }

    // staging = layer-1 aggregation for this block's 64 rows -> fp16 LDS
#pragma unroll
    for (int p = 0; p < 4; p++) {
        int row = p * 16 + (tid >> 4);
        int node = r0 + row;
        int c = (tid & 15) * 4;
        float4 acc = make_float4(0.f, 0.f, 0.f, 0.f);
        if (node < N) {
            h4 sv = *(const h4*)&A[(size_t)node * 64 + c];
            float2 f0 = __half22float2(sv.a);
            float2 f1 = __half22float2(sv.b);
            acc = make_float4(f0.x, f0.y, f1.x, f1.y);
            int e0 = rowptr[node], e1 = rowptr[node + 1];
            int e = e0;
            for (; e + 4 <= e1; e += 4) {
                int s0 = col[e + 0], s1 = col[e + 1], s2 = col[e + 2], s3 = col[e + 3];
                h4 v0 = *(const h4*)&A[(size_t)s0 * 64 + c];
                h4 v1 = *(const h4*)&A[(size_t)s1 * 64 + c];
                h4 v2 = *(const h4*)&A[(size_t)s2 * 64 + c];
                h4 v3 = *(const h4*)&A[(size_t)s3 * 64 + c];
                float2 a0 = __half22float2(v0.a), b0 = __half22float2(v0.b);
                float2 a1 = __half22float2(v1.a), b1 = __half22float2(v1.b);
                float2 a2 = __half22float2(v2.a), b2 = __half22float2(v2.b);
                float2 a3 = __half22float2(v3.a), b3 = __half22float2(v3.b);
                acc.x += a0.x + a1.x + a2.x + a3.x;
                acc.y += a0.y + a1.y + a2.y + a3.y;
                acc.z += b0.x + b1.x + b2.x + b3.x;
                acc.w += b0.y + b1.y + b2.y + b3.y;
            }
            for (; e < e1; e++) {
                int s = col[e];
                h4 v = *(const h4*)&A[(size_t)s * 64 + c];
                float2 a = __half22float2(v.a), b = __half22float2(v.b);
                acc.x += a.x; acc.y += a.y; acc.z += b.x; acc.w += b.y;
            }
            float dv = dinv[node];
            float4 b4 = *(const float4*)&b_prev[c];
            acc.x = fmaxf(acc.x * dv + b4.x, 0.f);
            acc.y = fmaxf(acc.y * dv + b4.y, 0.f);
            acc.z = fmaxf(acc.z * dv + b4.z, 0.f);
            acc.w = fmaxf(acc.w * dv + b4.w, 0.f);
        }
        v4h o;
        o.x = (_Float16)acc.x; o.y = (_Float16)acc.y;
        o.z = (_Float16)acc.z; o.w = (_Float16)acc.w;
        *(v4h*)&Xh[row][c] = o;
    }
    __syncthreads();

    // MFMA: wave wv handles 16-row strip, 4 col-tiles of 16, K=64 in 4 steps.
    const int wv = tid >> 6;
    const int lane = tid & 63;
    const int lr = lane & 15;      // A row / B col / C col within tile
    const int kg = lane >> 4;      // k group 0..3

    v4f acc0 = {0.f, 0.f, 0.f, 0.f};
    v4f acc1 = {0.f, 0.f, 0.f, 0.f};
    v4f acc2 = {0.f, 0.f, 0.f, 0.f};
    v4f acc3 = {0.f, 0.f, 0.f, 0.f};
#pragma unroll
    for (int s = 0; s < 4; s++) {
        v4h af = *(const v4h*)&Xh[wv * 16 + lr][s * 16 + kg * 4];
        v4h bf0 = *(const v4h*)&WhT[0 * 16 + lr][s * 16 + kg * 4];
        v4h bf1 = *(const v4h*)&WhT[1 * 16 + lr][s * 16 + kg * 4];
        v4h bf2 = *(const v4h*)&WhT[2 * 16 + lr][s * 16 + kg * 4];
        v4h bf3 = *(const v4h*)&WhT[3 * 16 + lr][s * 16 + kg * 4];
        acc0 = __builtin_amdgcn_mfma_f32_16x16x16f16(af, bf0, acc0, 0, 0, 0);
        acc1 = __builtin_amdgcn_mfma_f32_16x16x16f16(af, bf1, acc1, 0, 0, 0);
        acc2 = __builtin_amdgcn_mfma_f32_16x16x16f16(af, bf2, acc2, 0, 0, 0);
        acc3 = __builtin_amdgcn_mfma_f32_16x16x16f16(af, bf3, acc3, 0, 0, 0);
    }

    // epilogue: C lane layout col=lr, row=kg*4+j (within the wave's 16-row strip)
#pragma unroll
    for (int j = 0; j < 4; j++) {
        int row = r0 + wv * 16 + kg * 4 + j;
        if (row >= N) continue;
        float dv = dinv[row];
        XW[(size_t)row * 64 +  0 + lr] = (__half)(acc0[j] * dv);
        XW[(size_t)row * 64 + 16 + lr] = (__half)(acc1[j] * dv);
        XW[(size_t)row * 64 + 32 + lr] = (__half)(acc2[j] * dv);
        XW[(size_t)row * 64 + 48 + lr] = (__half)(acc3[j] * dv);
    }
}

// Pooling fused with layer-2 aggregation. 2 graphs per 128-thread block
// (one wave each): 16 lanes/node x 4 node-parallel sub-groups per wave.
__global__ __launch_bounds__(128) void segmean_agg(const int* __restrict__ rowptr,
                                                   const int* __restrict__ col,
                                                   const __half* __restrict__ A2,
                                                   const float* __restrict__ b2,
                                                   const float* __restrict__ dinv,
                                                   const int* __restrict__ batch,
                                                   float* __restrict__ M,
                                                   float* __restrict__ bscale,
                                                   int N, int G) {
    int g = blockIdx.x * 2 + (threadIdx.x >> 6);
    if (g >= G) return;
    int lane = threadIdx.x & 15;          // column group
    int sub  = (threadIdx.x >> 4) & 3;    // node-parallel sub-group in wave
    int c = lane * 4;

    int lo = 0, hi = N;
    while (lo < hi) { int m = (lo + hi) >> 1; if (batch[m] < g) lo = m + 1; else hi = m; }
    int start = lo;
    hi = N;
    while (lo < hi) { int m = (lo + hi) >> 1; if (batch[m] < g + 1) lo = m + 1; else hi = m; }
    int end = lo;

    float4 b4 = *(const float4*)&b2[c];
    float4 msum = make_float4(0.f, 0.f, 0.f, 0.f);

    for (int node = start + sub; node < end; node += 4) {
        h4 sv = *(const h4*)&A2[(size_t)node * 64 + c];
        float2 f0 = __half22float2(sv.a);
        float2 f1 = __half22float2(sv.b);
        float4 acc = make_float4(f0.x, f0.y, f1.x, f1.y);
        int e0 = rowptr[node], e1 = rowptr[node + 1];
        int e = e0;
        for (; e + 4 <= e1; e += 4) {
            int s0 = col[e + 0], s1 = col[e + 1], s2 = col[e + 2], s3 = col[e + 3];
            h4 v0 = *(const h4*)&A2[(size_t)s0 * 64 + c];
            h4 v1 = *(const h4*)&A2[(size_t)s1 * 64 + c];
            h4 v2 = *(const h4*)&A2[(size_t)s2 * 64 + c];
            h4 v3 = *(const h4*)&A2[(size_t)s3 * 64 + c];
            float2 a0 = __half22float2(v0.a), q0 = __half22float2(v0.b);
            float2 a1 = __half22float2(v1.a), q1 = __half22float2(v1.b);
            float2 a2 = __half22float2(v2.a), q2 = __half22float2(v2.b);
            float2 a3 = __half22float2(v3.a), q3 = __half22float2(v3.b);
            acc.x += a0.x + a1.x + a2.x + a3.x;
            acc.y += a0.y + a1.y + a2.y + a3.y;
            acc.z += q0.x + q1.x + q2.x + q3.x;
            acc.w += q0.y + q1.y + q2.y + q3.y;
        }
        for (; e < e1; e++) {
            int s = col[e];
            h4 v = *(const h4*)&A2[(size_t)s * 64 + c];
            float2 a = __half22float2(v.a), q = __half22float2(v.b);
            acc.x += a.x; acc.y += a.y; acc.z += q.x; acc.w += q.y;
        }
        float dv = dinv[node];
        msum.x += fmaxf(acc.x * dv + b4.x, 0.f);
        msum.y += fmaxf(acc.y * dv + b4.y, 0.f);
        msum.z += fmaxf(acc.z * dv + b4.z, 0.f);
        msum.w += fmaxf(acc.w * dv + b4.w, 0.f);
    }

    // reduce across the 4 sub-groups (within this graph's wave)
    msum.x += __shfl_xor(msum.x, 16); msum.y += __shfl_xor(msum.y, 16);
    msum.z += __shfl_xor(msum.z, 16); msum.w += __shfl_xor(msum.w, 16);
    msum.x += __shfl_xor(msum.x, 32); msum.y += __shfl_xor(msum.y, 32);
    msum.z += __shfl_xor(msum.z, 32); msum.w += __shfl_xor(msum.w, 32);

    int cnt = end - start;
    float inv = (cnt > 0) ? 1.f / (float)cnt : 0.f;
    if (sub == 0) {
        float4 o;
        o.x = msum.x * inv; o.y = msum.y * inv;
        o.z = msum.z * inv; o.w = msum.w * inv;
        *(float4*)&M[(size_t)g * 64 + c] = o;
        if (lane == 0) bscale[g] = (cnt > 0) ? 1.f : 0.f;
    }
}

// loc = M @ FW1 + bscale*Fb1   [G x 64 @ 64 x 128]; grid.y = 2 col-tiles.
__global__ __launch_bounds__(256) void loc_gemm(const float* __restrict__ M,
                                                const float* __restrict__ FW1,
                                                const float* __restrict__ Fb1,
                                                const float* __restrict__ bscale,
                                                float* __restrict__ loc, int G) {
    __shared__ float Xs[64][68];
    __shared__ float Ws[64][64];
    __shared__ float bs[64];
    const int tid = threadIdx.x;
    const int tc = tid & 15;
    const int tr = tid >> 4;
    const int r0 = blockIdx.x * 64;
    const int c0 = blockIdx.y * 64;

    for (int i = tid; i < 4096; i += 256)
        Ws[i >> 6][i & 63] = FW1[(size_t)(i >> 6) * 128 + c0 + (i & 63)];
    if (tid < 64) bs[tid] = Fb1[c0 + tid];
#pragma unroll
    for (int p = 0; p < 4; p++) {
        int row = p * 16 + (tid >> 4);
        int col = (tid & 15) * 4;
        float4 v = make_float4(0.f, 0.f, 0.f, 0.f);
        if (r0 + row < G) v = *(const float4*)&M[(size_t)(r0 + row) * 64 + col];
        *(float4*)&Xs[row][col] = v;
    }
    __syncthreads();

    float acc[4][4];
#pragma unroll
    for (int i = 0; i < 4; i++)
#pragma unroll
        for (int j = 0; j < 4; j++) acc[i][j] = 0.f;

#pragma unroll 8
    for (int k = 0; k < 64; k++) {
        float4 wv = *(const float4*)&Ws[k][tc * 4];
        float x0 = Xs[tr * 4 + 0][k];
        float x1 = Xs[tr * 4 + 1][k];
        float x2 = Xs[tr * 4 + 2][k];
        float x3 = Xs[tr * 4 + 3][k];
        acc[0][0] += x0 * wv.x; acc[0][1] += x0 * wv.y; acc[0][2] += x0 * wv.z; acc[0][3] += x0 * wv.w;
        acc[1][0] += x1 * wv.x; acc[1][1] += x1 * wv.y; acc[1][2] += x1 * wv.z; acc[1][3] += x1 * wv.w;
        acc[2][0] += x2 * wv.x; acc[2][1] += x2 * wv.y; acc[2][2] += x2 * wv.z; acc[2][3] += x2 * wv.w;
        acc[3][0] += x3 * wv.x; acc[3][1] += x3 * wv.y; acc[3][2] += x3 * wv.z; acc[3][3] += x3 * wv.w;
    }

#pragma unroll
    for (int i = 0; i < 4; i++) {
        int row = r0 + tr * 4 + i;
        if (row >= G) continue;
        float sc = bscale[row];
        float4 o;
        o.x = acc[i][0] + sc * bs[tc * 4 + 0];
        o.y = acc[i][1] + sc * bs[tc * 4 + 1];
        o.z = acc[i][2] + sc * bs[tc * 4 + 2];
        o.w = acc[i][3] + sc * bs[tc * 4 + 3];
        *(float4*)&loc[(size_t)row * 128 + c0 + tc * 4] = o;
    }
}

// ic = loc @ FW2 + Fb2; thread 0 also writes the trailing scalar 0.
__global__ __launch_bounds__(256) void ic_kernel(const float* __restrict__ loc,
                                                 const float* __restrict__ FW2,
                                                 const float* __restrict__ Fb2,
                                                 float* __restrict__ ic,
                                                 float* __restrict__ scalar_out, int G) {
    __shared__ float Ws[1280];
    __shared__ float bs[10];
    for (int i = threadIdx.x; i < 1280; i += 256) Ws[i] = FW2[i];
    if (threadIdx.x < 10) bs[threadIdx.x] = Fb2[threadIdx.x];
    __syncthreads();
    int g = blockIdx.x * 256 + threadIdx.x;
    if (g == 0) scalar_out[0] = 0.f;
    if (g >= G) return;
    float acc[10];
#pragma unroll
    for (int j = 0; j < 10; j++) acc[j] = bs[j];
    const float* xr = loc + (size_t)g * 128;
    for (int k = 0; k < 128; k++) {
        float xv = xr[k];
#pragma unroll
        for (int j = 0; j < 10; j++) acc[j] += xv * Ws[k * 10 + j];
    }
    float* o = ic + (size_t)g * 10;
#pragma unroll
    for (int j = 0; j < 10; j++) o[j] = acc[j];
}

// ZW = (X @ W) * dinv[row]  [G x 128 @ 128 x 128]; 64x64 tile (grid.y = 2 col tiles).
__global__ __launch_bounds__(256) void gemm_g128(const float* __restrict__ X,
                                                 const float* __restrict__ W,
                                                 const float* __restrict__ dinv,
                                                 float* __restrict__ ZW, int G) {
    __shared__ float Xs[64][68];
    __shared__ float Ws[64][64];
    const int tid = threadIdx.x;
    const int tc = tid & 15;
    const int tr = tid >> 4;
    const int r0 = blockIdx.x * 64;
    const int c0 = blockIdx.y * 64;

    float acc[4][4];
#pragma unroll
    for (int i = 0; i < 4; i++)
#pragma unroll
        for (int j = 0; j < 4; j++) acc[i][j] = 0.f;

    for (int kc = 0; kc < 2; kc++) {
        __syncthreads();
        for (int i = tid; i < 4096; i += 256)
            Ws[i >> 6][i & 63] = W[(size_t)(kc * 64 + (i >> 6)) * 128 + c0 + (i & 63)];
#pragma unroll
        for (int p = 0; p < 4; p++) {
            int row = p * 16 + (tid >> 4);
            int col = (tid & 15) * 4;
            float4 v = make_float4(0.f, 0.f, 0.f, 0.f);
            if (r0 + row < G) v = *(const float4*)&X[(size_t)(r0 + row) * 128 + kc * 64 + col];
            *(float4*)&Xs[row][col] = v;
        }
        __syncthreads();
#pragma unroll 8
        for (int k = 0; k < 64; k++) {
            float4 wv = *(const float4*)&Ws[k][tc * 4];
            float x0 = Xs[tr * 4 + 0][k];
            float x1 = Xs[tr * 4 + 1][k];
            float x2 = Xs[tr * 4 + 2][k];
            float x3 = Xs[tr * 4 + 3][k];
            acc[0][0] += x0 * wv.x; acc[0][1] += x0 * wv.y; acc[0][2] += x0 * wv.z; acc[0][3] += x0 * wv.w;
            acc[1][0] += x1 * wv.x; acc[1][1] += x1 * wv.y; acc[1][2] += x1 * wv.z; acc[1][3] += x1 * wv.w;
            acc[2][0] += x2 * wv.x; acc[2][1] += x2 * wv.y; acc[2][2] += x2 * wv.z; acc[2][3] += x2 * wv.w;
            acc[3][0] += x3 * wv.x; acc[3][1] += x3 * wv.y; acc[3][2] += x3 * wv.z; acc[3][3] += x3 * wv.w;
        }
    }

#pragma unroll
    for (int i = 0; i < 4; i++) {
        int row = r0 + tr * 4 + i;
        if (row >= G) continue;
        float dv = dinv[row];
        *(float4*)&ZW[(size_t)row * 128 + c0 + tc * 4] =
            make_float4(acc[i][0] * dv, acc[i][1] * dv, acc[i][2] * dv, acc[i][3] * dv);
    }
}

// ZW = X @ W [G x 128 @ 128 x 10]; HC = ZW*mdrecip + bias
__global__ __launch_bounds__(256) void gemm_g10(const float* __restrict__ X,
                                                const float* __restrict__ W,
                                                const float* __restrict__ bias,
                                                const float* __restrict__ mdrecip,
                                                float* __restrict__ ZW,
                                                float* __restrict__ HC, int G) {
    __shared__ float Ws[1280];
    __shared__ float bs[10];
    for (int i = threadIdx.x; i < 1280; i += 256) Ws[i] = W[i];
    if (threadIdx.x < 10) bs[threadIdx.x] = bias[threadIdx.x];
    __syncthreads();
    int g = blockIdx.x * 256 + threadIdx.x;
    if (g >= G) return;
    float acc[10];
#pragma unroll
    for (int j = 0; j < 10; j++) acc[j] = 0.f;
    const float4* xr = (const float4*)(X + (size_t)g * 128);
#pragma unroll 4
    for (int k4 = 0; k4 < 32; k4++) {
        float4 v = xr[k4];
        float xv[4] = {v.x, v.y, v.z, v.w};
#pragma unroll
        for (int d = 0; d < 4; d++) {
            float xs = xv[d];
            int k = k4 * 4 + d;
#pragma unroll
            for (int j = 0; j < 10; j++) acc[j] += xs * Ws[k * 10 + j];
        }
    }
    float dr = mdrecip[g];
    float* zw = ZW + (size_t)g * 10;
    float* hc = HC + (size_t)g * 10;
#pragma unroll
    for (int j = 0; j < 10; j++) {
        zw[j] = acc[j];
        hc[j] = acc[j] * dr + bs[j];
    }
}

// HC[md] += ZW[ms] * mdinv[ms]*mdinv[md]  (10 features, tiny)
__global__ void edge_agg10(const int* __restrict__ ms, const int* __restrict__ md,
                           const float* __restrict__ mdinv, const float* __restrict__ ZW,
                           float* __restrict__ HC, int EM) {
    int e = blockIdx.x * blockDim.x + threadIdx.x;
    if (e >= EM) return;
    int s = ms[e], d = md[e];
    float w = mdinv[s] * mdinv[d];
    const float* zr = ZW + (size_t)s * 10;
    float* out = HC + (size_t)d * 10;
#pragma unroll
    for (int j = 0; j < 10; j++) atomicAdd(out + j, zr[j] * w);
}

extern "C" void kernel_launch(void* const* d_in, const int* in_sizes, int n_in,
                              void* d_out, int out_size, void* d_ws, size_t ws_size,
                              hipStream_t stream) {
    const float* x    = (const float*)d_in[0];
    const int*   ei   = (const int*)d_in[1];
    const int*   batch= (const int*)d_in[2];
    const int*   me   = (const int*)d_in[3];
    const float* W1   = (const float*)d_in[5];
    const float* b1   = (const float*)d_in[6];
    const float* W2   = (const float*)d_in[7];
    const float* b2   = (const float*)d_in[8];
    const float* FW1  = (const float*)d_in[9];
    const float* Fb1  = (const float*)d_in[10];
    const float* FW2  = (const float*)d_in[11];
    const float* Fb2  = (const float*)d_in[12];
    const float* MW1  = (const float*)d_in[13];
    const float* mb1  = (const float*)d_in[14];
    const float* g1   = (const float*)d_in[15];
    const float* be1  = (const float*)d_in[16];
    const float* m1   = (const float*)d_in[17];
    const float* v1   = (const float*)d_in[18];
    const float* MW2  = (const float*)d_in[19];
    const float* mb2  = (const float*)d_in[20];
    const float* g2   = (const float*)d_in[21];
    const float* be2  = (const float*)d_in[22];
    const float* m2   = (const float*)d_in[23];
    const float* v2   = (const float*)d_in[24];
    const float* MW3  = (const float*)d_in[25];
    const float* mb3  = (const float*)d_in[26];

    const int N  = in_sizes[0] / 64;
    const int E  = in_sizes[1] / 2;
    const int EM = in_sizes[3] / 2;
    const int G  = (out_size - 1) / 276;

    float* out    = (float*)d_out;
    float* hc     = out;
    float* ic     = out + (size_t)G * 10;
    float* loc    = out + (size_t)G * 20;
    float* glob   = out + (size_t)G * 20 + (size_t)G * 128;
    float* scalar = out + (size_t)G * 276;

    char*  ws  = (char*)d_ws;
    size_t off = 0;
    auto alloc = [&](size_t bytes) -> void* {
        void* p = (void*)(ws + off);
        off += (bytes + 255) & ~(size_t)255;
        return p;
    };
    int*    hist    = (int*)alloc((size_t)(N + 1) * 4);
    int*    rowptr  = (int*)alloc((size_t)(N + 1) * 4);
    int*    cursor  = (int*)alloc((size_t)N * 4);
    int*    bsum    = (int*)alloc(512 * 4);
    int*    col     = (int*)alloc((size_t)E * 4);
    float*  dinv    = (float*)alloc((size_t)N * 4);
    float*  drecip  = (float*)alloc((size_t)N * 4);
    int*    mhist   = (int*)alloc((size_t)(G + 1) * 4);
    int*    mrowptr = (int*)alloc((size_t)(G + 1) * 4);
    int*    mcursor = (int*)alloc((size_t)G * 4);
    int*    mbsum   = (int*)alloc(512 * 4);
    int*    mcol    = (int*)alloc((size_t)EM * 4);
    float*  mdinv   = (float*)alloc((size_t)G * 4);
    float*  mdrecip = (float*)alloc((size_t)G * 4);
    __half* A       = (__half*)alloc((size_t)N * 64 * 2);   // fp16 xw1*dinv
    __half* A2      = (__half*)alloc((size_t)N * 64 * 2);   // fp16 xw2*dinv
    float*  M       = (float*)alloc((size_t)G * 64 * 4);    // segment means
    float*  bscale  = (float*)alloc((size_t)G * 4);
    float*  mzw     = (float*)alloc((size_t)G * 128 * 4);
    float*  z1      = (float*)alloc((size_t)G * 128 * 4);
    float*  zw3     = (float*)alloc((size_t)G * 10 * 4);
    (void)ws_size;

    const int* src = ei;
    const int* dst = ei + E;
    const int* ms  = me;
    const int* md  = me + EM;

    // ---- degrees + CSR build (node graph and macro graph) ----
    hipMemsetAsync(hist, 0, (size_t)(N + 1) * 4, stream);
    hipMemsetAsync(mhist, 0, (size_t)(G + 1) * 4, stream);
    hist_kernel<<<(E + 255) / 256, 256, 0, stream>>>(dst, hist, E);
    hist_kernel<<<(EM + 255) / 256, 256, 0, stream>>>(md, mhist, EM);
    finalize_deg<<<(N + 255) / 256, 256, 0, stream>>>(hist, dinv, drecip, N);
    finalize_deg<<<(G + 255) / 256, 256, 0, stream>>>(mhist, mdinv, mdrecip, G);

    const int nb1 = (N + 1023) / 1024;
    scan1<<<nb1, 256, 0, stream>>>(hist, rowptr, bsum, N);
    scan2<<<1, 512, 0, stream>>>(bsum, nb1);
    scan3<<<(N + 255) / 256, 256, 0, stream>>>(rowptr, bsum, cursor, N, E);
    const int nb2 = (G + 1023) / 1024;
    scan1<<<nb2, 256, 0, stream>>>(mhist, mrowptr, mbsum, G);
    scan2<<<1, 512, 0, stream>>>(mbsum, nb2);
    scan3<<<(G + 255) / 256, 256, 0, stream>>>(mrowptr, mbsum, mcursor, G, EM);

    {
        const int nchunks = 2048;
        const int per_chunk = (E + nchunks - 1) / nchunks;
        const int npx = (N + 7) / 8;
        scatter_xcd<<<nchunks * 8, 256, 0, stream>>>(src, dst, cursor, col, E, per_chunk, npx);
    }
    scatter_kernel<<<(EM + 255) / 256, 256, 0, stream>>>(ms, md, mcursor, mcol, EM);

    const int nblk = (N + 63) / 64;

    // Layer 1 GEMM -> fp16 A
    gemm_n64<<<nblk, 256, 0, stream>>>(x, W1, dinv, A, N);
    // Layer 2: fused layer-1 aggregation + MFMA GEMM -> fp16 A2
    gemm_agg_n64<<<nblk, 256, 0, stream>>>(rowptr, col, A, b1, W2, dinv, A2, N);
    // Pooling with fused layer-2 aggregation (2 graphs/block)
    segmean_agg<<<(G + 1) / 2, 128, 0, stream>>>(rowptr, col, A2, b2, dinv, batch, M, bscale, N, G);
    {
        dim3 lg((G + 63) / 64, 2);
        loc_gemm<<<lg, 256, 0, stream>>>(M, FW1, Fb1, bscale, loc, G);
    }
    ic_kernel<<<(G + 255) / 256, 256, 0, stream>>>(loc, FW2, Fb2, ic, scalar, G);

    dim3 mg((G + 63) / 64, 2);

    // Macro layer 1 (agg + BN + relu fused)
    gemm_g128<<<mg, 256, 0, stream>>>(loc, MW1, mdinv, mzw, G);
    csr_agg_bn128<<<(G * 32 + 255) / 256, 256, 0, stream>>>(mrowptr, mcol, mzw, mb1, mdinv,
                                                            g1, be1, m1, v1, z1, G);
    // Macro layer 2 -> glob (in d_out)
    gemm_g128<<<mg, 256, 0, stream>>>(z1, MW2, mdinv, mzw, G);
    csr_agg_bn128<<<(G * 32 + 255) / 256, 256, 0, stream>>>(mrowptr, mcol, mzw, mb2, mdinv,
                                                            g2, be2, m2, v2, glob, G);

    // hc = GCN(glob, MW3, mb3)
    gemm_g10<<<(G + 255) / 256, 256, 0, stream>>>(glob, MW3, mb3, mdrecip, zw3, hc, G);
    edge_agg10<<<(EM + 255) / 256, 256, 0, stream>>>(ms, md, mdinv, zw3, hc, EM);
}

// Round 13
// 705.727 us; speedup vs baseline: 1.3062x; 1.0256x over previous
//
#include <hip/hip_runtime.h>
#include <hip/hip_fp16.h>

// ---------------------------------------------------------------------------
// SEAL GNN pipeline.
// R13: segmean_agg made NODE-parallel (was graph-parallel, 52% occ, serial
// ~50-node walk per wave). Now: 64 consecutive nodes per 256-thread block
// (16 thr/node gather staging into LDS, like gemm_agg), then a sorted-batch
// per-column run-accumulate with one atomicAdd per graph-span per column
// into M (pre-zeroed; inv_cnt folded in). Counts via per-graph binsearch.
// ---------------------------------------------------------------------------

typedef float nf4 __attribute__((ext_vector_type(4)));
typedef _Float16 v4h __attribute__((ext_vector_type(4)));
typedef float v4f __attribute__((ext_vector_type(4)));
struct __align__(8) h4 { __half2 a, b; };

__global__ void hist_kernel(const int* __restrict__ dst, int* __restrict__ hist, int E) {
    int e = blockIdx.x * blockDim.x + threadIdx.x;
    if (e < E) atomicAdd(&hist[dst[e]], 1);
}

__global__ void finalize_deg(const int* __restrict__ hist, float* __restrict__ dinv,
                             float* __restrict__ drecip, int n) {
    int i = blockIdx.x * blockDim.x + threadIdx.x;
    if (i < n) {
        float c = (float)hist[i] + 1.0f;   // self-loop included
        dinv[i]   = rsqrtf(c);
        drecip[i] = 1.0f / c;
    }
}

// Per-graph node counts (batch sorted): inv count + bscale.
__global__ void gcnt_kernel(const int* __restrict__ batch, float* __restrict__ invc,
                            float* __restrict__ bscale, int N, int G) {
    int g = blockIdx.x * blockDim.x + threadIdx.x;
    if (g >= G) return;
    int lo = 0, hi = N;
    while (lo < hi) { int m = (lo + hi) >> 1; if (batch[m] < g) lo = m + 1; else hi = m; }
    int s = lo;
    hi = N;
    while (lo < hi) { int m = (lo + hi) >> 1; if (batch[m] < g + 1) lo = m + 1; else hi = m; }
    int cnt = lo - s;
    invc[g]   = (cnt > 0) ? 1.f / (float)cnt : 0.f;
    bscale[g] = (cnt > 0) ? 1.f : 0.f;
}

// Exclusive scan, stage 1: 1024 counts per 256-thread block.
__global__ __launch_bounds__(256) void scan1(const int* __restrict__ cnt, int* __restrict__ pre,
                                             int* __restrict__ bsum, int n) {
    __shared__ int s[256];
    int base = blockIdx.x * 1024;
    int t = threadIdx.x;
    int v[4];
    int loc = 0;
#pragma unroll
    for (int j = 0; j < 4; j++) {
        int i = base + t * 4 + j;
        v[j] = (i < n) ? cnt[i] : 0;
        loc += v[j];
    }
    s[t] = loc;
    __syncthreads();
    for (int off = 1; off < 256; off <<= 1) {
        int x = (t >= off) ? s[t - off] : 0;
        __syncthreads();
        s[t] += x;
        __syncthreads();
    }
    int run = s[t] - loc;
    if (t == 255) bsum[blockIdx.x] = s[255];
#pragma unroll
    for (int j = 0; j < 4; j++) {
        int i = base + t * 4 + j;
        if (i < n) pre[i] = run;
        run += v[j];
    }
}

// Stage 2: exclusive scan of block sums in place (nb <= 512).
__global__ __launch_bounds__(512) void scan2(int* __restrict__ bsum, int nb) {
    __shared__ int s[512];
    int t = threadIdx.x;
    int v = (t < nb) ? bsum[t] : 0;
    s[t] = v;
    __syncthreads();
    for (int off = 1; off < 512; off <<= 1) {
        int x = (t >= off) ? s[t - off] : 0;
        __syncthreads();
        s[t] += x;
        __syncthreads();
    }
    if (t < nb) bsum[t] = s[t] - v;
}

// Stage 3: add block offsets; also initializes cursor; writes rowptr[n] = E.
__global__ void scan3(int* __restrict__ pre, const int* __restrict__ bsum,
                      int* __restrict__ cursor, int n, int E) {
    int i = blockIdx.x * blockDim.x + threadIdx.x;
    if (i < n) {
        int v = pre[i] + bsum[i >> 10];
        pre[i] = v;
        cursor[i] = v;
    }
    if (i == 0) pre[n] = E;
}

// XCD-bucketed scatter (see R6 comment).
__global__ __launch_bounds__(256) void scatter_xcd(const int* __restrict__ src,
                                                   const int* __restrict__ dst,
                                                   int* __restrict__ cursor,
                                                   int* __restrict__ col,
                                                   int E, int per_chunk, int npx) {
    int bucket = blockIdx.x & 7;
    int chunk  = blockIdx.x >> 3;
    int lo = bucket * npx;
    int hi = lo + npx;
    int e0 = chunk * per_chunk;
    int e1 = min(e0 + per_chunk, E);
    for (int e = e0 + threadIdx.x; e < e1; e += 256) {
        int d = dst[e];
        if (d < lo || d >= hi) continue;
        int p = atomicAdd(&cursor[d], 1);
        col[p] = src[e];
    }
}

// Simple scatter for the tiny macro graph.
__global__ void scatter_kernel(const int* __restrict__ src, const int* __restrict__ dst,
                               int* __restrict__ cursor, int* __restrict__ col, int E) {
    int e = blockIdx.x * blockDim.x + threadIdx.x;
    if (e >= E) return;
    int p = atomicAdd(&cursor[dst[e]], 1);
    col[p] = src[e];
}

// Macro aggregation with fused BatchNorm(eval)+ReLU (fp32, tiny).
__global__ __launch_bounds__(256) void csr_agg_bn128(const int* __restrict__ rowptr,
                                                     const int* __restrict__ col,
                                                     const float* __restrict__ A,
                                                     const float* __restrict__ bias,
                                                     const float* __restrict__ dinv,
                                                     const float* __restrict__ gam,
                                                     const float* __restrict__ bet,
                                                     const float* __restrict__ mean,
                                                     const float* __restrict__ var,
                                                     float* __restrict__ Z, int N) {
    constexpr int F = 128, TPN = 32, NPB = 8;
    int node = blockIdx.x * NPB + threadIdx.x / TPN;
    int lane = threadIdx.x % TPN;
    if (node >= N) return;
    int c = lane * 4;
    float4 acc = *(const float4*)&A[(size_t)node * F + c];
    int e0 = rowptr[node], e1 = rowptr[node + 1];
    int e = e0;
    for (; e + 4 <= e1; e += 4) {
        int s0 = col[e + 0], s1 = col[e + 1], s2 = col[e + 2], s3 = col[e + 3];
        float4 v0 = *(const float4*)&A[(size_t)s0 * F + c];
        float4 v1 = *(const float4*)&A[(size_t)s1 * F + c];
        float4 v2 = *(const float4*)&A[(size_t)s2 * F + c];
        float4 v3 = *(const float4*)&A[(size_t)s3 * F + c];
        acc.x += v0.x + v1.x + v2.x + v3.x;
        acc.y += v0.y + v1.y + v2.y + v3.y;
        acc.z += v0.z + v1.z + v2.z + v3.z;
        acc.w += v0.w + v1.w + v2.w + v3.w;
    }
    for (; e < e1; e++) {
        int s = col[e];
        float4 v = *(const float4*)&A[(size_t)s * F + c];
        acc.x += v.x; acc.y += v.y; acc.z += v.z; acc.w += v.w;
    }
    float dv = dinv[node];
    float4 b4 = *(const float4*)&bias[c];
    float4 g4 = *(const float4*)&gam[c];
    float4 be4 = *(const float4*)&bet[c];
    float4 m4 = *(const float4*)&mean[c];
    float4 v4 = *(const float4*)&var[c];
    float4 o;
    o.x = fmaxf((acc.x * dv + b4.x - m4.x) * rsqrtf(v4.x + 1e-5f) * g4.x + be4.x, 0.f);
    o.y = fmaxf((acc.y * dv + b4.y - m4.y) * rsqrtf(v4.y + 1e-5f) * g4.y + be4.y, 0.f);
    o.z = fmaxf((acc.z * dv + b4.z - m4.z) * rsqrtf(v4.z + 1e-5f) * g4.z + be4.z, 0.f);
    o.w = fmaxf((acc.w * dv + b4.w - m4.w) * rsqrtf(v4.w + 1e-5f) * g4.w + be4.w, 0.f);
    *(float4*)&Z[(size_t)node * F + c] = o;
}

// Layer-1 GEMM: A_h = fp16( (X @ W1) * dinv[row] ). W from global (L1-resident).
__global__ __launch_bounds__(256) void gemm_n64(const float* __restrict__ X,
                                                const float* __restrict__ W,
                                                const float* __restrict__ dinv,
                                                __half* __restrict__ XW, int N) {
    __shared__ float Xs[64][68];
    const int tid = threadIdx.x;
    const int tc = tid & 15;
    const int tr = tid >> 4;
    const int r0 = blockIdx.x * 64;

#pragma unroll
    for (int p = 0; p < 4; p++) {
        int row = p * 16 + (tid >> 4);
        int col = (tid & 15) * 4;
        float4 v = make_float4(0.f, 0.f, 0.f, 0.f);
        if (r0 + row < N) {
            nf4 nv = __builtin_nontemporal_load((const nf4*)&X[(size_t)(r0 + row) * 64 + col]);
            v = make_float4(nv.x, nv.y, nv.z, nv.w);
        }
        *(float4*)&Xs[row][col] = v;
    }
    __syncthreads();

    float acc[4][4];
#pragma unroll
    for (int i = 0; i < 4; i++)
#pragma unroll
        for (int j = 0; j < 4; j++) acc[i][j] = 0.f;

    const float* wp = W + tc * 4;
#pragma unroll 8
    for (int k = 0; k < 64; k++) {
        float4 wv = *(const float4*)&wp[k * 64];
        float x0 = Xs[tr * 4 + 0][k];
        float x1 = Xs[tr * 4 + 1][k];
        float x2 = Xs[tr * 4 + 2][k];
        float x3 = Xs[tr * 4 + 3][k];
        acc[0][0] += x0 * wv.x; acc[0][1] += x0 * wv.y; acc[0][2] += x0 * wv.z; acc[0][3] += x0 * wv.w;
        acc[1][0] += x1 * wv.x; acc[1][1] += x1 * wv.y; acc[1][2] += x1 * wv.z; acc[1][3] += x1 * wv.w;
        acc[2][0] += x2 * wv.x; acc[2][1] += x2 * wv.y; acc[2][2] += x2 * wv.z; acc[2][3] += x2 * wv.w;
        acc[3][0] += x3 * wv.x; acc[3][1] += x3 * wv.y; acc[3][2] += x3 * wv.z; acc[3][3] += x3 * wv.w;
    }

#pragma unroll
    for (int i = 0; i < 4; i++) {
        int row = r0 + tr * 4 + i;
        if (row >= N) continue;
        float dv = dinv[row];
        h4 o;
        o.a = __floats2half2_rn(acc[i][0] * dv, acc[i][1] * dv);
        o.b = __floats2half2_rn(acc[i][2] * dv, acc[i][3] * dv);
        *(h4*)&XW[(size_t)row * 64 + tc * 4] = o;
    }
}

// Layer-2 fused: X-tile = relu(dinv*(A[row]+sum A[col]) + b_prev) staged fp16
// into LDS, then A2 = fp16((X @ W2) * dinv[row]) via MFMA 16x16x16 f16.
__global__ __launch_bounds__(256) void gemm_agg_n64(const int* __restrict__ rowptr,
                                                    const int* __restrict__ col,
                                                    const __half* __restrict__ A,
                                                    const float* __restrict__ b_prev,
                                                    const float* __restrict__ W,
                                                    const float* __restrict__ dinv,
                                                    __half* __restrict__ XW, int N) {
    __shared__ _Float16 Xh[64][68];
    __shared__ _Float16 WhT[64][68];
    const int tid = threadIdx.x;
    const int r0 = blockIdx.x * 64;

    for (int i = tid; i < 4096; i += 256) {
        int k = i >> 6, c = i & 63;
        WhT[c][k] = (_Float16)W[i];
    }

#pragma unroll
    for (int p = 0; p < 4; p++) {
        int row = p * 16 + (tid >> 4);
        int node = r0 + row;
        int c = (tid & 15) * 4;
        float4 acc = make_float4(0.f, 0.f, 0.f, 0.f);
        if (node < N) {
            h4 sv = *(const h4*)&A[(size_t)node * 64 + c];
            float2 f0 = __half22float2(sv.a);
            float2 f1 = __half22float2(sv.b);
            acc = make_float4(f0.x, f0.y, f1.x, f1.y);
            int e0 = rowptr[node], e1 = rowptr[node + 1];
            int e = e0;
            for (; e + 4 <= e1; e += 4) {
                int s0 = col[e + 0], s1 = col[e + 1], s2 = col[e + 2], s3 = col[e + 3];
                h4 v0 = *(const h4*)&A[(size_t)s0 * 64 + c];
                h4 v1 = *(const h4*)&A[(size_t)s1 * 64 + c];
                h4 v2 = *(const h4*)&A[(size_t)s2 * 64 + c];
                h4 v3 = *(const h4*)&A[(size_t)s3 * 64 + c];
                float2 a0 = __half22float2(v0.a), b0 = __half22float2(v0.b);
                float2 a1 = __half22float2(v1.a), b1 = __half22float2(v1.b);
                float2 a2 = __half22float2(v2.a), b2 = __half22float2(v2.b);
                float2 a3 = __half22float2(v3.a), b3 = __half22float2(v3.b);
                acc.x += a0.x + a1.x + a2.x + a3.x;
                acc.y += a0.y + a1.y + a2.y + a3.y;
                acc.z += b0.x + b1.x + b2.x + b3.x;
                acc.w += b0.y + b1.y + b2.y + b3.y;
            }
            for (; e < e1; e++) {
                int s = col[e];
                h4 v = *(const h4*)&A[(size_t)s * 64 + c];
                float2 a = __half22float2(v.a), b = __half22float2(v.b);
                acc.x += a.x; acc.y += a.y; acc.z += b.x; acc.w += b.y;
            }
            float dv = dinv[node];
            float4 b4 = *(const float4*)&b_prev[c];
            acc.x = fmaxf(acc.x * dv + b4.x, 0.f);
            acc.y = fmaxf(acc.y * dv + b4.y, 0.f);
            acc.z = fmaxf(acc.z * dv + b4.z, 0.f);
            acc.w = fmaxf(acc.w * dv + b4.w, 0.f);
        }
        v4h o;
        o.x = (_Float16)acc.x; o.y = (_Float16)acc.y;
        o.z = (_Float16)acc.z; o.w = (_Float16)acc.w;
        *(v4h*)&Xh[row][c] = o;
    }
    __syncthreads();

    const int wv = tid >> 6;
    const int lane = tid & 63;
    const int lr = lane & 15;
    const int kg = lane >> 4;

    v4f acc0 = {0.f, 0.f, 0.f, 0.f};
    v4f acc1 = {0.f, 0.f, 0.f, 0.f};
    v4f acc2 = {0.f, 0.f, 0.f, 0.f};
    v4f acc3 = {0.f, 0.f, 0.f, 0.f};
#pragma unroll
    for (int s = 0; s < 4; s++) {
        v4h af = *(const v4h*)&Xh[wv * 16 + lr][s * 16 + kg * 4];
        v4h bf0 = *(const v4h*)&WhT[0 * 16 + lr][s * 16 + kg * 4];
        v4h bf1 = *(const v4h*)&WhT[1 * 16 + lr][s * 16 + kg * 4];
        v4h bf2 = *(const v4h*)&WhT[2 * 16 + lr][s * 16 + kg * 4];
        v4h bf3 = *(const v4h*)&WhT[3 * 16 + lr][s * 16 + kg * 4];
        acc0 = __builtin_amdgcn_mfma_f32_16x16x16f16(af, bf0, acc0, 0, 0, 0);
        acc1 = __builtin_amdgcn_mfma_f32_16x16x16f16(af, bf1, acc1, 0, 0, 0);
        acc2 = __builtin_amdgcn_mfma_f32_16x16x16f16(af, bf2, acc2, 0, 0, 0);
        acc3 = __builtin_amdgcn_mfma_f32_16x16x16f16(af, bf3, acc3, 0, 0, 0);
    }

#pragma unroll
    for (int j = 0; j < 4; j++) {
        int row = r0 + wv * 16 + kg * 4 + j;
        if (row >= N) continue;
        float dv = dinv[row];
        XW[(size_t)row * 64 +  0 + lr] = (__half)(acc0[j] * dv);
        XW[(size_t)row * 64 + 16 + lr] = (__half)(acc1[j] * dv);
        XW[(size_t)row * 64 + 32 + lr] = (__half)(acc2[j] * dv);
        XW[(size_t)row * 64 + 48 + lr] = (__half)(acc3[j] * dv);
    }
}

// Node-parallel pooling+aggregation: block = 64 consecutive nodes; stage
// relu'd agg rows in LDS, then per-column sorted-run accumulate into M
// (inv_cnt folded; M pre-zeroed; few atomics per block).
__global__ __launch_bounds__(256) void segmean_agg(const int* __restrict__ rowptr,
                                                   const int* __restrict__ col,
                                                   const __half* __restrict__ A2,
                                                   const float* __restrict__ b2,
                                                   const float* __restrict__ dinv,
                                                   const int* __restrict__ batch,
                                                   const float* __restrict__ invc,
                                                   float* __restrict__ M, int N) {
    __shared__ float Xs[64][68];
    __shared__ int gb[64];
    const int tid = threadIdx.x;
    const int r0 = blockIdx.x * 64;

    if (tid < 64) gb[tid] = (r0 + tid < N) ? batch[r0 + tid] : -1;

#pragma unroll
    for (int p = 0; p < 4; p++) {
        int row = p * 16 + (tid >> 4);
        int node = r0 + row;
        int c = (tid & 15) * 4;
        float4 acc = make_float4(0.f, 0.f, 0.f, 0.f);
        if (node < N) {
            h4 sv = *(const h4*)&A2[(size_t)node * 64 + c];
            float2 f0 = __half22float2(sv.a);
            float2 f1 = __half22float2(sv.b);
            acc = make_float4(f0.x, f0.y, f1.x, f1.y);
            int e0 = rowptr[node], e1 = rowptr[node + 1];
            int e = e0;
            for (; e + 4 <= e1; e += 4) {
                int s0 = col[e + 0], s1 = col[e + 1], s2 = col[e + 2], s3 = col[e + 3];
                h4 v0 = *(const h4*)&A2[(size_t)s0 * 64 + c];
                h4 v1 = *(const h4*)&A2[(size_t)s1 * 64 + c];
                h4 v2 = *(const h4*)&A2[(size_t)s2 * 64 + c];
                h4 v3 = *(const h4*)&A2[(size_t)s3 * 64 + c];
                float2 a0 = __half22float2(v0.a), q0 = __half22float2(v0.b);
                float2 a1 = __half22float2(v1.a), q1 = __half22float2(v1.b);
                float2 a2 = __half22float2(v2.a), q2 = __half22float2(v2.b);
                float2 a3 = __half22float2(v3.a), q3 = __half22float2(v3.b);
                acc.x += a0.x + a1.x + a2.x + a3.x;
                acc.y += a0.y + a1.y + a2.y + a3.y;
                acc.z += q0.x + q1.x + q2.x + q3.x;
                acc.w += q0.y + q1.y + q2.y + q3.y;
            }
            for (; e < e1; e++) {
                int s = col[e];
                h4 v = *(const h4*)&A2[(size_t)s * 64 + c];
                float2 a = __half22float2(v.a), q = __half22float2(v.b);
                acc.x += a.x; acc.y += a.y; acc.z += q.x; acc.w += q.y;
            }
            float dv = dinv[node];
            float4 b4 = *(const float4*)&b2[c];
            acc.x = fmaxf(acc.x * dv + b4.x, 0.f);
            acc.y = fmaxf(acc.y * dv + b4.y, 0.f);
            acc.z = fmaxf(acc.z * dv + b4.z, 0.f);
            acc.w = fmaxf(acc.w * dv + b4.w, 0.f);
        }
        *(float4*)&Xs[row][c] = acc;
    }
    __syncthreads();

    // per-column run-accumulate over the sorted 64 rows
    if (tid < 64) {
        int t = tid;
        float run = 0.f;
        int curg = gb[0];
        for (int r = 0; r < 64; r++) {
            int g2 = gb[r];
            if (g2 != curg) {
                if (curg >= 0) atomicAdd(&M[(size_t)curg * 64 + t], run * invc[curg]);
                run = 0.f;
                curg = g2;
            }
            if (g2 >= 0) run += Xs[r][t];
        }
        if (curg >= 0) atomicAdd(&M[(size_t)curg * 64 + t], run * invc[curg]);
    }
}

// loc = M @ FW1 + bscale*Fb1   [G x 64 @ 64 x 128]; grid.y = 2 col-tiles.
__global__ __launch_bounds__(256) void loc_gemm(const float* __restrict__ M,
                                                const float* __restrict__ FW1,
                                                const float* __restrict__ Fb1,
                                                const float* __restrict__ bscale,
                                                float* __restrict__ loc, int G) {
    __shared__ float Xs[64][68];
    __shared__ float Ws[64][64];
    __shared__ float bs[64];
    const int tid = threadIdx.x;
    const int tc = tid & 15;
    const int tr = tid >> 4;
    const int r0 = blockIdx.x * 64;
    const int c0 = blockIdx.y * 64;

    for (int i = tid; i < 4096; i += 256)
        Ws[i >> 6][i & 63] = FW1[(size_t)(i >> 6) * 128 + c0 + (i & 63)];
    if (tid < 64) bs[tid] = Fb1[c0 + tid];
#pragma unroll
    for (int p = 0; p < 4; p++) {
        int row = p * 16 + (tid >> 4);
        int col = (tid & 15) * 4;
        float4 v = make_float4(0.f, 0.f, 0.f, 0.f);
        if (r0 + row < G) v = *(const float4*)&M[(size_t)(r0 + row) * 64 + col];
        *(float4*)&Xs[row][col] = v;
    }
    __syncthreads();

    float acc[4][4];
#pragma unroll
    for (int i = 0; i < 4; i++)
#pragma unroll
        for (int j = 0; j < 4; j++) acc[i][j] = 0.f;

#pragma unroll 8
    for (int k = 0; k < 64; k++) {
        float4 wv = *(const float4*)&Ws[k][tc * 4];
        float x0 = Xs[tr * 4 + 0][k];
        float x1 = Xs[tr * 4 + 1][k];
        float x2 = Xs[tr * 4 + 2][k];
        float x3 = Xs[tr * 4 + 3][k];
        acc[0][0] += x0 * wv.x; acc[0][1] += x0 * wv.y; acc[0][2] += x0 * wv.z; acc[0][3] += x0 * wv.w;
        acc[1][0] += x1 * wv.x; acc[1][1] += x1 * wv.y; acc[1][2] += x1 * wv.z; acc[1][3] += x1 * wv.w;
        acc[2][0] += x2 * wv.x; acc[2][1] += x2 * wv.y; acc[2][2] += x2 * wv.z; acc[2][3] += x2 * wv.w;
        acc[3][0] += x3 * wv.x; acc[3][1] += x3 * wv.y; acc[3][2] += x3 * wv.z; acc[3][3] += x3 * wv.w;
    }

#pragma unroll
    for (int i = 0; i < 4; i++) {
        int row = r0 + tr * 4 + i;
        if (row >= G) continue;
        float sc = bscale[row];
        float4 o;
        o.x = acc[i][0] + sc * bs[tc * 4 + 0];
        o.y = acc[i][1] + sc * bs[tc * 4 + 1];
        o.z = acc[i][2] + sc * bs[tc * 4 + 2];
        o.w = acc[i][3] + sc * bs[tc * 4 + 3];
        *(float4*)&loc[(size_t)row * 128 + c0 + tc * 4] = o;
    }
}

// ic = loc @ FW2 + Fb2; thread 0 also writes the trailing scalar 0.
__global__ __launch_bounds__(256) void ic_kernel(const float* __restrict__ loc,
                                                 const float* __restrict__ FW2,
                                                 const float* __restrict__ Fb2,
                                                 float* __restrict__ ic,
                                                 float* __restrict__ scalar_out, int G) {
    __shared__ float Ws[1280];
    __shared__ float bs[10];
    for (int i = threadIdx.x; i < 1280; i += 256) Ws[i] = FW2[i];
    if (threadIdx.x < 10) bs[threadIdx.x] = Fb2[threadIdx.x];
    __syncthreads();
    int g = blockIdx.x * 256 + threadIdx.x;
    if (g == 0) scalar_out[0] = 0.f;
    if (g >= G) return;
    float acc[10];
#pragma unroll
    for (int j = 0; j < 10; j++) acc[j] = bs[j];
    const float* xr = loc + (size_t)g * 128;
    for (int k = 0; k < 128; k++) {
        float xv = xr[k];
#pragma unroll
        for (int j = 0; j < 10; j++) acc[j] += xv * Ws[k * 10 + j];
    }
    float* o = ic + (size_t)g * 10;
#pragma unroll
    for (int j = 0; j < 10; j++) o[j] = acc[j];
}

// ZW = (X @ W) * dinv[row]  [G x 128 @ 128 x 128]; 64x64 tile (grid.y = 2 col tiles).
__global__ __launch_bounds__(256) void gemm_g128(const float* __restrict__ X,
                                                 const float* __restrict__ W,
                                                 const float* __restrict__ dinv,
                                                 float* __restrict__ ZW, int G) {
    __shared__ float Xs[64][68];
    __shared__ float Ws[64][64];
    const int tid = threadIdx.x;
    const int tc = tid & 15;
    const int tr = tid >> 4;
    const int r0 = blockIdx.x * 64;
    const int c0 = blockIdx.y * 64;

    float acc[4][4];
#pragma unroll
    for (int i = 0; i < 4; i++)
#pragma unroll
        for (int j = 0; j < 4; j++) acc[i][j] = 0.f;

    for (int kc = 0; kc < 2; kc++) {
        __syncthreads();
        for (int i = tid; i < 4096; i += 256)
            Ws[i >> 6][i & 63] = W[(size_t)(kc * 64 + (i >> 6)) * 128 + c0 + (i & 63)];
#pragma unroll
        for (int p = 0; p < 4; p++) {
            int row = p * 16 + (tid >> 4);
            int col = (tid & 15) * 4;
            float4 v = make_float4(0.f, 0.f, 0.f, 0.f);
            if (r0 + row < G) v = *(const float4*)&X[(size_t)(r0 + row) * 128 + kc * 64 + col];
            *(float4*)&Xs[row][col] = v;
        }
        __syncthreads();
#pragma unroll 8
        for (int k = 0; k < 64; k++) {
            float4 wv = *(const float4*)&Ws[k][tc * 4];
            float x0 = Xs[tr * 4 + 0][k];
            float x1 = Xs[tr * 4 + 1][k];
            float x2 = Xs[tr * 4 + 2][k];
            float x3 = Xs[tr * 4 + 3][k];
            acc[0][0] += x0 * wv.x; acc[0][1] += x0 * wv.y; acc[0][2] += x0 * wv.z; acc[0][3] += x0 * wv.w;
            acc[1][0] += x1 * wv.x; acc[1][1] += x1 * wv.y; acc[1][2] += x1 * wv.z; acc[1][3] += x1 * wv.w;
            acc[2][0] += x2 * wv.x; acc[2][1] += x2 * wv.y; acc[2][2] += x2 * wv.z; acc[2][3] += x2 * wv.w;
            acc[3][0] += x3 * wv.x; acc[3][1] += x3 * wv.y; acc[3][2] += x3 * wv.z; acc[3][3] += x3 * wv.w;
        }
    }

#pragma unroll
    for (int i = 0; i < 4; i++) {
        int row = r0 + tr * 4 + i;
        if (row >= G) continue;
        float dv = dinv[row];
        *(float4*)&ZW[(size_t)row * 128 + c0 + tc * 4] =
            make_float4(acc[i][0] * dv, acc[i][1] * dv, acc[i][2] * dv, acc[i][3] * dv);
    }
}

// ZW = X @ W [G x 128 @ 128 x 10]; HC = ZW*mdrecip + bias
__global__ __launch_bounds__(256) void gemm_g10(const float* __restrict__ X,
                                                const float* __restrict__ W,
                                                const float* __restrict__ bias,
                                                const float* __restrict__ mdrecip,
                                                float* __restrict__ ZW,
                                                float* __restrict__ HC, int G) {
    __shared__ float Ws[1280];
    __shared__ float bs[10];
    for (int i = threadIdx.x; i < 1280; i += 256) Ws[i] = W[i];
    if (threadIdx.x < 10) bs[threadIdx.x] = bias[threadIdx.x];
    __syncthreads();
    int g = blockIdx.x * 256 + threadIdx.x;
    if (g >= G) return;
    float acc[10];
#pragma unroll
    for (int j = 0; j < 10; j++) acc[j] = 0.f;
    const float4* xr = (const float4*)(X + (size_t)g * 128);
#pragma unroll 4
    for (int k4 = 0; k4 < 32; k4++) {
        float4 v = xr[k4];
        float xv[4] = {v.x, v.y, v.z, v.w};
#pragma unroll
        for (int d = 0; d < 4; d++) {
            float xs = xv[d];
            int k = k4 * 4 + d;
#pragma unroll
            for (int j = 0; j < 10; j++) acc[j] += xs * Ws[k * 10 + j];
        }
    }
    float dr = mdrecip[g];
    float* zw = ZW + (size_t)g * 10;
    float* hc = HC + (size_t)g * 10;
#pragma unroll
    for (int j = 0; j < 10; j++) {
        zw[j] = acc[j];
        hc[j] = acc[j] * dr + bs[j];
    }
}

// HC[md] += ZW[ms] * mdinv[ms]*mdinv[md]  (10 features, tiny)
__global__ void edge_agg10(const int* __restrict__ ms, const int* __restrict__ md,
                           const float* __restrict__ mdinv, const float* __restrict__ ZW,
                           float* __restrict__ HC, int EM) {
    int e = blockIdx.x * blockDim.x + threadIdx.x;
    if (e >= EM) return;
    int s = ms[e], d = md[e];
    float w = mdinv[s] * mdinv[d];
    const float* zr = ZW + (size_t)s * 10;
    float* out = HC + (size_t)d * 10;
#pragma unroll
    for (int j = 0; j < 10; j++) atomicAdd(out + j, zr[j] * w);
}

extern "C" void kernel_launch(void* const* d_in, const int* in_sizes, int n_in,
                              void* d_out, int out_size, void* d_ws, size_t ws_size,
                              hipStream_t stream) {
    const float* x    = (const float*)d_in[0];
    const int*   ei   = (const int*)d_in[1];
    const int*   batch= (const int*)d_in[2];
    const int*   me   = (const int*)d_in[3];
    const float* W1   = (const float*)d_in[5];
    const float* b1   = (const float*)d_in[6];
    const float* W2   = (const float*)d_in[7];
    const float* b2   = (const float*)d_in[8];
    const float* FW1  = (const float*)d_in[9];
    const float* Fb1  = (const float*)d_in[10];
    const float* FW2  = (const float*)d_in[11];
    const float* Fb2  = (const float*)d_in[12];
    const float* MW1  = (const float*)d_in[13];
    const float* mb1  = (const float*)d_in[14];
    const float* g1   = (const float*)d_in[15];
    const float* be1  = (const float*)d_in[16];
    const float* m1   = (const float*)d_in[17];
    const float* v1   = (const float*)d_in[18];
    const float* MW2  = (const float*)d_in[19];
    const float* mb2  = (const float*)d_in[20];
    const float* g2   = (const float*)d_in[21];
    const float* be2  = (const float*)d_in[22];
    const float* m2   = (const float*)d_in[23];
    const float* v2   = (const float*)d_in[24];
    const float* MW3  = (const float*)d_in[25];
    const float* mb3  = (const float*)d_in[26];

    const int N  = in_sizes[0] / 64;
    const int E  = in_sizes[1] / 2;
    const int EM = in_sizes[3] / 2;
    const int G  = (out_size - 1) / 276;

    float* out    = (float*)d_out;
    float* hc     = out;
    float* ic     = out + (size_t)G * 10;
    float* loc    = out + (size_t)G * 20;
    float* glob   = out + (size_t)G * 20 + (size_t)G * 128;
    float* scalar = out + (size_t)G * 276;

    char*  ws  = (char*)d_ws;
    size_t off = 0;
    auto alloc = [&](size_t bytes) -> void* {
        void* p = (void*)(ws + off);
        off += (bytes + 255) & ~(size_t)255;
        return p;
    };
    int*    hist    = (int*)alloc((size_t)(N + 1) * 4);
    int*    rowptr  = (int*)alloc((size_t)(N + 1) * 4);
    int*    cursor  = (int*)alloc((size_t)N * 4);
    int*    bsum    = (int*)alloc(512 * 4);
    int*    col     = (int*)alloc((size_t)E * 4);
    float*  dinv    = (float*)alloc((size_t)N * 4);
    float*  drecip  = (float*)alloc((size_t)N * 4);
    int*    mhist   = (int*)alloc((size_t)(G + 1) * 4);
    int*    mrowptr = (int*)alloc((size_t)(G + 1) * 4);
    int*    mcursor = (int*)alloc((size_t)G * 4);
    int*    mbsum   = (int*)alloc(512 * 4);
    int*    mcol    = (int*)alloc((size_t)EM * 4);
    float*  mdinv   = (float*)alloc((size_t)G * 4);
    float*  mdrecip = (float*)alloc((size_t)G * 4);
    __half* A       = (__half*)alloc((size_t)N * 64 * 2);   // fp16 xw1*dinv
    __half* A2      = (__half*)alloc((size_t)N * 64 * 2);   // fp16 xw2*dinv
    float*  M       = (float*)alloc((size_t)G * 64 * 4);    // segment means (atomic)
    float*  invc    = (float*)alloc((size_t)G * 4);
    float*  bscale  = (float*)alloc((size_t)G * 4);
    float*  mzw     = (float*)alloc((size_t)G * 128 * 4);
    float*  z1      = (float*)alloc((size_t)G * 128 * 4);
    float*  zw3     = (float*)alloc((size_t)G * 10 * 4);
    (void)ws_size;

    const int* src = ei;
    const int* dst = ei + E;
    const int* ms  = me;
    const int* md  = me + EM;

    // ---- degrees + CSR build (node graph and macro graph) ----
    hipMemsetAsync(hist, 0, (size_t)(N + 1) * 4, stream);
    hipMemsetAsync(mhist, 0, (size_t)(G + 1) * 4, stream);
    hipMemsetAsync(M, 0, (size_t)G * 64 * 4, stream);
    hist_kernel<<<(E + 255) / 256, 256, 0, stream>>>(dst, hist, E);
    hist_kernel<<<(EM + 255) / 256, 256, 0, stream>>>(md, mhist, EM);
    finalize_deg<<<(N + 255) / 256, 256, 0, stream>>>(hist, dinv, drecip, N);
    finalize_deg<<<(G + 255) / 256, 256, 0, stream>>>(mhist, mdinv, mdrecip, G);
    gcnt_kernel<<<(G + 255) / 256, 256, 0, stream>>>(batch, invc, bscale, N, G);

    const int nb1 = (N + 1023) / 1024;
    scan1<<<nb1, 256, 0, stream>>>(hist, rowptr, bsum, N);
    scan2<<<1, 512, 0, stream>>>(bsum, nb1);
    scan3<<<(N + 255) / 256, 256, 0, stream>>>(rowptr, bsum, cursor, N, E);
    const int nb2 = (G + 1023) / 1024;
    scan1<<<nb2, 256, 0, stream>>>(mhist, mrowptr, mbsum, G);
    scan2<<<1, 512, 0, stream>>>(mbsum, nb2);
    scan3<<<(G + 255) / 256, 256, 0, stream>>>(mrowptr, mbsum, mcursor, G, EM);

    {
        const int nchunks = 2048;
        const int per_chunk = (E + nchunks - 1) / nchunks;
        const int npx = (N + 7) / 8;
        scatter_xcd<<<nchunks * 8, 256, 0, stream>>>(src, dst, cursor, col, E, per_chunk, npx);
    }
    scatter_kernel<<<(EM + 255) / 256, 256, 0, stream>>>(ms, md, mcursor, mcol, EM);

    const int nblk = (N + 63) / 64;

    // Layer 1 GEMM -> fp16 A
    gemm_n64<<<nblk, 256, 0, stream>>>(x, W1, dinv, A, N);
    // Layer 2: fused layer-1 aggregation + MFMA GEMM -> fp16 A2
    gemm_agg_n64<<<nblk, 256, 0, stream>>>(rowptr, col, A, b1, W2, dinv, A2, N);
    // Pooling with fused layer-2 aggregation (node-parallel, sorted-run atomics)
    segmean_agg<<<nblk, 256, 0, stream>>>(rowptr, col, A2, b2, dinv, batch, invc, M, N);
    {
        dim3 lg((G + 63) / 64, 2);
        loc_gemm<<<lg, 256, 0, stream>>>(M, FW1, Fb1, bscale, loc, G);
    }
    ic_kernel<<<(G + 255) / 256, 256, 0, stream>>>(loc, FW2, Fb2, ic, scalar, G);

    dim3 mg((G + 63) / 64, 2);

    // Macro layer 1 (agg + BN + relu fused)
    gemm_g128<<<mg, 256, 0, stream>>>(loc, MW1, mdinv, mzw, G);
    csr_agg_bn128<<<(G * 32 + 255) / 256, 256, 0, stream>>>(mrowptr, mcol, mzw, mb1, mdinv,
                                                            g1, be1, m1, v1, z1, G);
    // Macro layer 2 -> glob (in d_out)
    gemm_g128<<<mg, 256, 0, stream>>>(z1, MW2, mdinv, mzw, G);
    csr_agg_bn128<<<(G * 32 + 255) / 256, 256, 0, stream>>>(mrowptr, mcol, mzw, mb2, mdinv,
                                                            g2, be2, m2, v2, glob, G);

    // hc = GCN(glob, MW3, mb3)
    gemm_g10<<<(G + 255) / 256, 256, 0, stream>>>(glob, MW3, mb3, mdrecip, zw3, hc, G);
    edge_agg10<<<(EM + 255) / 256, 256, 0, stream>>>(ms, md, mdinv, zw3, hc, EM);
}